// Round 5
// baseline (5441.052 us; speedup 1.0000x reference)
//
#include <hip/hip_runtime.h>

// Masked GRU (RNNStateEncoder), T=256, N=128, D=H=1024.
// Single persistent step kernel: 256 WGs x 512 threads (8 waves, 2/SIMD).
// Each WG owns 32 batch rows x 16 h-cols. Per step:
//   - h-GEMM (W_hh LDS-resident, XOR-swizzled), K split 4-way across waves
//   - xp[t+1] GEMM computed in-register (x from HBM, W_ih from L2) - no
//     separate xproj kernel, no xp buffer (WG consumes its own slice)
//   - 4 independent barrier groups of 64 WGs (one per 32-row block):
//     release fetch_add + relaxed poll + single acquire
// h carried as hi/lo bf16 split for precision.
// Fallback (ws too small): round-2 monolithic persistent kernel.

#define TSTEPS 256
#define NBATCH 128
#define DDIM   1024
#define HDIM   1024

typedef short  bf16x8 __attribute__((ext_vector_type(8)));
typedef float  f32x4  __attribute__((ext_vector_type(4)));

// ---- ws layout (bytes) ----
#define CTR_OFF      0                          // 4 groups x 256 B
#define BAR_CTR_OFF  1024                       // fallback
#define BAR_GEN_OFF  1028                       // fallback
#define MFLAG_OFF    2048
#define WIH_OFF      4096
#define WHH_OFF      (WIH_OFF + 6291456)        // 6295552
#define HHI_OFF      (WHH_OFF + 6291456)        // 12587008 : ushort hhi[2][128*1024]
#define HLO_OFF      (HHI_OFF + 524288)         // 13111296 : ushort hlo[2][128*1024]
#define HF_OFF       (HLO_OFF + 524288)         // 13635584 : float h[2][128*1024] (fallback)
#define WS_NEED      (HF_OFF + 1048576ull)      // ~14.7 MB

#define SCOPE_AGENT __HIP_MEMORY_SCOPE_AGENT

__device__ __forceinline__ unsigned short f2bf(float f) {
    union { float f; unsigned u; } v; v.f = f;
    unsigned r = v.u + 0x7FFFu + ((v.u >> 16) & 1u);   // RNE
    return (unsigned short)(r >> 16);
}
__device__ __forceinline__ float bf2f(unsigned short h) {
    union { unsigned u; float f; } v; v.u = ((unsigned)h) << 16;
    return v.f;
}

__device__ __forceinline__ float mask_val(const void* m, int fmt, int idx) {
    if (fmt == 0) return ((const unsigned char*)m)[idx] ? 1.f : 0.f;
    if (fmt == 1) return ((const int*)m)[idx] ? 1.f : 0.f;
    return (((const float*)m)[idx] != 0.f) ? 1.f : 0.f;
}

// ---- detect mask dtype: 0 = bool bytes, 1 = int32, 2 = float32 ----
__global__ void detect_mask(const unsigned char* __restrict__ m8, int* __restrict__ flag) {
    __shared__ int s_ones, s_c01, s_cf;
    if (threadIdx.x == 0) { s_ones = 0; s_c01 = 0; s_cf = 0; }
    __syncthreads();
    int ones = 0;
    for (int i = threadIdx.x; i < 4096; i += 256) ones += (m8[i] == 1);
    int c01 = 0, cf = 0;
    const unsigned* m32 = (const unsigned*)m8;
    for (int i = threadIdx.x; i < 1024; i += 256) {
        unsigned v = m32[i];
        c01 += (v <= 1u);
        cf  += (v == 0u || v == 0x3F800000u);
    }
    atomicAdd(&s_ones, ones); atomicAdd(&s_c01, c01); atomicAdd(&s_cf, cf);
    __syncthreads();
    if (threadIdx.x == 0) *flag = (s_ones > 2048) ? 0 : ((s_c01 >= s_cf) ? 1 : 2);
}

// ---- convert both weight matrices to bf16 (row-major (3072,1024)) ----
__global__ void conv_w(const float* __restrict__ wih, const float* __restrict__ whh,
                       unsigned short* __restrict__ wih_b, unsigned short* __restrict__ whh_b) {
    size_t i = ((size_t)blockIdx.x * 256 + threadIdx.x) * 4;
    if (i >= (size_t)3145728) return;
    float4 a = *(const float4*)(wih + i);
    ushort4 ra; ra.x = f2bf(a.x); ra.y = f2bf(a.y); ra.z = f2bf(a.z); ra.w = f2bf(a.w);
    *(ushort4*)(wih_b + i) = ra;
    float4 b = *(const float4*)(whh + i);
    ushort4 rb; rb.x = f2bf(b.x); rb.y = f2bf(b.y); rb.z = f2bf(b.z); rb.w = f2bf(b.w);
    *(ushort4*)(whh_b + i) = rb;
}

// ---- init h0 (pre-masked with m[0]) into buffer 0 ----
__global__ void init_h(const float* __restrict__ h0, const unsigned char* __restrict__ masks,
                       const int* __restrict__ flag,
                       float* __restrict__ hf, unsigned short* __restrict__ hhi,
                       unsigned short* __restrict__ hlo) {
    int i = (blockIdx.x * 256 + threadIdx.x) * 4;
    if (i >= NBATCH * HDIM) return;
    int fmt = *flag;
    int n = i >> 10;
    float m = mask_val(masks, fmt, n);
    float4 a = *(const float4*)(h0 + i);
    float v[4] = { a.x * m, a.y * m, a.z * m, a.w * m };
#pragma unroll
    for (int q = 0; q < 4; ++q) {
        hf[i + q] = v[q];
        unsigned short hi = f2bf(v[q]);
        hhi[i + q] = hi;
        hlo[i + q] = f2bf(v[q] - bf2f(hi));
    }
}

// ============== main persistent GRU kernel: 256 WGs x 512 threads ==============
__launch_bounds__(512, 2)
__global__ void gru_seq(const float* __restrict__ x,
                        const unsigned char* __restrict__ masks,
                        const int* __restrict__ mflag,
                        const float* __restrict__ bih,
                        const float* __restrict__ bhh,
                        const unsigned short* __restrict__ wih,
                        const unsigned short* __restrict__ whh,
                        const float* __restrict__ h0,
                        float* __restrict__ out,
                        unsigned short* __restrict__ hhi,
                        unsigned short* __restrict__ hlo,
                        unsigned* __restrict__ ctrs) {
    const int bid  = blockIdx.x;
    const int cb   = bid >> 2;          // 0..63 : 16 h-cols
    const int rb   = bid & 3;           // 0..3  : 32 batch rows; barrier group
    const int tid  = threadIdx.x;
    const int wave = tid >> 6;          // 0..7
    const int lane = tid & 63;
    const int l15  = lane & 15;
    const int l4   = lane >> 4;
    const int rt   = wave >> 2;         // row-tile 0..1
    const int kq   = wave & 3;          // K quarter 0..3
    const int mfmt = *mflag;
    const int an   = rb * 32 + rt * 16 + l15;    // A-fragment batch row

    __shared__ __align__(16) unsigned short Wl[49152];  // W_hh slice 48x1024, swizzled
    __shared__ __align__(16) f32x4 Pl[1536];            // 8 waves x 64 lanes x 3 ct
    float* Plf = (float*)Pl;

    // ---- stage W_hh slice into LDS ----
#pragma unroll
    for (int it = 0; it < 12; ++it) {
        const int ck = it * 512 + tid;          // 0..6143 16B chunks
        const int sr = ck >> 7;                 // 0..47
        const int kc = ck & 127;
        const int grow = (sr >> 4) * 1024 + cb * 16 + (sr & 15);
        bf16x8 v = *(const bf16x8*)(whh + (size_t)grow * 1024 + kc * 8);
        const int byte = (sr * 2048 + kc * 16) ^ ((sr & 7) << 4);
        *(bf16x8*)((char*)Wl + byte) = v;
    }

    // ---- per-thread output mapping: 1 (row, col) each ----
    const int r = tid >> 4, c = tid & 15;
    const int n = rb * 32 + r;
    const int j = cb * 16 + c;
    const int rtp = r >> 4, ip = r & 3;
    const int lanep = ((r >> 2) & 3) * 16 + c;
    const float bir = bih[j], biz = bih[1024 + j], bin = bih[2048 + j];
    const float bhr = bhh[j], bhz = bhh[1024 + j], bhn = bhh[2048 + j];

    float hold = h0[(size_t)n * 1024 + j] * mask_val(masks, mfmt, n);
    float mn   = mask_val(masks, mfmt, NBATCH + n);     // mask[t=1]

    unsigned* ctr = ctrs + rb * 64;     // 256 B apart per group

    const f32x4 zz = {0.f, 0.f, 0.f, 0.f};

    // xp GEMM for time tt (own slice, in registers)
    auto xp_compute = [&](int tt, f32x4* axx) {
        axx[0] = zz; axx[1] = zz; axx[2] = zz;
        const float* xrow = x + ((size_t)tt * NBATCH + an) * 1024 + kq * 256 + l4 * 8;
#pragma unroll
        for (int kt = 0; kt < 8; ++kt) {
            float4 u0 = *(const float4*)(xrow + kt * 32);
            float4 u1 = *(const float4*)(xrow + kt * 32 + 4);
            bf16x8 a;
            a[0] = (short)f2bf(u0.x); a[1] = (short)f2bf(u0.y);
            a[2] = (short)f2bf(u0.z); a[3] = (short)f2bf(u0.w);
            a[4] = (short)f2bf(u1.x); a[5] = (short)f2bf(u1.y);
            a[6] = (short)f2bf(u1.z); a[7] = (short)f2bf(u1.w);
#pragma unroll
            for (int ct = 0; ct < 3; ++ct) {
                const bf16x8 bw = *(const bf16x8*)(wih +
                    (size_t)(ct * 1024 + cb * 16 + l15) * 1024 + kq * 256 + kt * 32 + l4 * 8);
                axx[ct] = __builtin_amdgcn_mfma_f32_16x16x32_bf16(a, bw, axx[ct], 0, 0, 0);
            }
        }
    };
    // per-thread 4-way K reduction from Pl
    auto redx = [&](int ct) -> float {
        float s = 0.f;
#pragma unroll
        for (int q = 0; q < 4; ++q)
            s += Plf[((((rtp * 4 + q) * 64 + lanep) * 3 + ct) << 2) + ip];
        return s;
    };

    // ---- prologue: xp[0] ----
    f32x4 axx[3];
    xp_compute(0, axx);
#pragma unroll
    for (int ct = 0; ct < 3; ++ct) Pl[(wave * 64 + lane) * 3 + ct] = axx[ct];
    __syncthreads();
    float xr  = redx(0) + bir;
    float xz  = redx(1) + biz;
    float xn_ = redx(2) + bin;
    __syncthreads();

    for (int t = 0; t < TSTEPS; ++t) {
        const int cur = t & 1, nxt = cur ^ 1;
        const unsigned short* hhi_c = hhi + (size_t)cur * (NBATCH * HDIM);
        const unsigned short* hlo_c = hlo + (size_t)cur * (NBATCH * HDIM);

        // preload full h K-chunk (16 loads in flight)
        bf16x8 ah[8], al[8];
        const unsigned short* hb = hhi_c + (size_t)an * 1024 + kq * 256 + l4 * 8;
        const unsigned short* lb = hlo_c + (size_t)an * 1024 + kq * 256 + l4 * 8;
#pragma unroll
        for (int kt = 0; kt < 8; ++kt) {
            ah[kt] = *(const bf16x8*)(hb + kt * 32);
            al[kt] = *(const bf16x8*)(lb + kt * 32);
        }

        // xp[t+1] overlaps h-load latency (x, W_ih independent of barrier)
        if (t < TSTEPS - 1) xp_compute(t + 1, axx);

        // h MFMAs from LDS W_hh
        f32x4 acch[3]; acch[0] = zz; acch[1] = zz; acch[2] = zz;
#pragma unroll
        for (int kt = 0; kt < 8; ++kt) {
            const int ktg = kq * 8 + kt;
#pragma unroll
            for (int ct = 0; ct < 3; ++ct) {
                const int sr = ct * 16 + l15;
                const int byte = (sr * 2048 + ktg * 64 + l4 * 16) ^ ((sr & 7) << 4);
                const bf16x8 bw = *(const bf16x8*)((char*)Wl + byte);
                acch[ct] = __builtin_amdgcn_mfma_f32_16x16x32_bf16(ah[kt], bw, acch[ct], 0, 0, 0);
                acch[ct] = __builtin_amdgcn_mfma_f32_16x16x32_bf16(al[kt], bw, acch[ct], 0, 0, 0);
            }
        }
#pragma unroll
        for (int ct = 0; ct < 3; ++ct) Pl[(wave * 64 + lane) * 3 + ct] = acch[ct];
        __syncthreads();                                        // #1: h partials ready

        // gates: 1 output per thread
        const float hr = redx(0) + bhr;
        const float hz = redx(1) + bhz;
        const float hn = redx(2) + bhn;
        const float rg = 1.f / (1.f + __expf(-(xr + hr)));
        const float zg = 1.f / (1.f + __expf(-(xz + hz)));
        const float nc = tanhf(xn_ + rg * hn);
        const float hnew = (1.f - zg) * nc + zg * hold;
        out[((size_t)t * NBATCH + n) * HDIM + j] = hnew;

        if (t == TSTEPS - 1) {
            out[(size_t)TSTEPS * NBATCH * HDIM + (size_t)n * HDIM + j] = hnew;
        } else {
            const float hm = hnew * mn;
            hold = hm;
            const size_t ho = (size_t)nxt * (NBATCH * HDIM) + (size_t)n * HDIM + j;
            const unsigned short hi = f2bf(hm);
            hhi[ho] = hi;
            hlo[ho] = f2bf(hm - bf2f(hi));

            __syncthreads();                                    // #2: stores drained
            if (tid == 0)
                __hip_atomic_fetch_add(ctr, 1u, __ATOMIC_RELEASE, SCOPE_AGENT);

            // local xp reduce overlaps other groups' progress
#pragma unroll
            for (int ct = 0; ct < 3; ++ct) Pl[(wave * 64 + lane) * 3 + ct] = axx[ct];
            __syncthreads();                                    // #3: xp partials ready
            xr  = redx(0) + bir;
            xz  = redx(1) + biz;
            xn_ = redx(2) + bin;
            mn  = (t + 2 < TSTEPS) ? mask_val(masks, mfmt, (t + 2) * NBATCH + n) : 0.f;

            if (tid == 0) {
                const unsigned tgt = 64u * (unsigned)(t + 1);
                while (__hip_atomic_load(ctr, __ATOMIC_RELAXED, SCOPE_AGENT) < tgt)
                    __builtin_amdgcn_s_sleep(1);
                (void)__hip_atomic_load(ctr, __ATOMIC_ACQUIRE, SCOPE_AGENT);  // single L2 inv
            }
            __syncthreads();                                    // #4: h[t+1] visible
        }
    }
}

// ============== Fallback: round-2 monolithic kernel (ws too small) ==============
__launch_bounds__(256)
__global__ void gru_main(const float* __restrict__ x,
                         const unsigned char* __restrict__ masks,
                         const float* __restrict__ bih, const float* __restrict__ bhh,
                         const unsigned short* __restrict__ wih,
                         const unsigned short* __restrict__ whh,
                         float* __restrict__ out,
                         float* __restrict__ hf,
                         unsigned short* __restrict__ hhi,
                         unsigned short* __restrict__ hlo,
                         int* __restrict__ bar_ctr, int* __restrict__ bar_gen,
                         const int* __restrict__ mflag) {
    const int bid  = blockIdx.x;
    const int xcd  = bid & 7;
    const int slot = bid >> 3;
    const int cb   = xcd * 2 + (slot >> 2);
    const int rb   = slot & 3;
    const int tid  = threadIdx.x;
    const int wid  = tid >> 6;
    const int lane = tid & 63;
    const int l15  = lane & 15;
    const int l4   = lane >> 4;
    const int mfmt = *mflag;

    __shared__ float xp_l[32][196];
    __shared__ float hp_l[32][196];

    int gbase[3];
#pragma unroll
    for (int c = 0; c < 3; ++c) {
        int ct = wid * 3 + c;
        gbase[c] = (ct >> 2) * 1024 + cb * 64 + (ct & 3) * 16;
    }

    for (int t = 0; t < TSTEPS; ++t) {
        const int cur = t & 1, nxt = cur ^ 1;
        f32x4 accx[2][3], acch[2][3];
        const f32x4 zz = {0.f, 0.f, 0.f, 0.f};
#pragma unroll
        for (int rt = 0; rt < 2; ++rt)
#pragma unroll
            for (int c = 0; c < 3; ++c) { accx[rt][c] = zz; acch[rt][c] = zz; }

        const unsigned short* hhi_c = hhi + (size_t)cur * (NBATCH * HDIM);
        const unsigned short* hlo_c = hlo + (size_t)cur * (NBATCH * HDIM);

        for (int kk = 0; kk < DDIM; kk += 32) {
            const int kb = kk + l4 * 8;
            bf16x8 axh[2], axl[2], ahh[2], ahl[2];
#pragma unroll
            for (int rt = 0; rt < 2; ++rt) {
                const int row = rb * 32 + rt * 16 + l15;
                const float* px = x + ((size_t)(t * NBATCH + row)) * DDIM + kb;
                float4 f0 = *(const float4*)px;
                float4 f1 = *(const float4*)(px + 4);
                float v[8] = { f0.x, f0.y, f0.z, f0.w, f1.x, f1.y, f1.z, f1.w };
#pragma unroll
                for (int q = 0; q < 8; ++q) {
                    unsigned short hi = f2bf(v[q]);
                    axh[rt][q] = (short)hi;
                    axl[rt][q] = (short)f2bf(v[q] - bf2f(hi));
                }
                const size_t hoff = (size_t)row * HDIM + kb;
                ahh[rt] = *(const bf16x8*)(hhi_c + hoff);
                ahl[rt] = *(const bf16x8*)(hlo_c + hoff);
            }
#pragma unroll
            for (int c = 0; c < 3; ++c) {
                const size_t wrow = (size_t)(gbase[c] + l15) * 1024 + kb;
                const bf16x8 bx = *(const bf16x8*)(wih + wrow);
                const bf16x8 bh = *(const bf16x8*)(whh + wrow);
#pragma unroll
                for (int rt = 0; rt < 2; ++rt) {
                    accx[rt][c] = __builtin_amdgcn_mfma_f32_16x16x32_bf16(axh[rt], bx, accx[rt][c], 0, 0, 0);
                    accx[rt][c] = __builtin_amdgcn_mfma_f32_16x16x32_bf16(axl[rt], bx, accx[rt][c], 0, 0, 0);
                    acch[rt][c] = __builtin_amdgcn_mfma_f32_16x16x32_bf16(ahh[rt], bh, acch[rt][c], 0, 0, 0);
                    acch[rt][c] = __builtin_amdgcn_mfma_f32_16x16x32_bf16(ahl[rt], bh, acch[rt][c], 0, 0, 0);
                }
            }
        }

#pragma unroll
        for (int c = 0; c < 3; ++c) {
            const int ct = wid * 3 + c;
#pragma unroll
            for (int rt = 0; rt < 2; ++rt) {
#pragma unroll
                for (int i = 0; i < 4; ++i) {
                    const int row = rt * 16 + l4 * 4 + i;
                    const int col = ct * 16 + l15;
                    xp_l[row][col] = accx[rt][c][i];
                    hp_l[row][col] = acch[rt][c][i];
                }
            }
        }
        __syncthreads();

#pragma unroll
        for (int u = 0; u < 8; ++u) {
            const int o   = u * 256 + tid;
            const int row = o >> 6;
            const int jj  = o & 63;
            const int nIdx = rb * 32 + row;
            const int gj   = cb * 64 + jj;
            const float xr = xp_l[row][jj],       hr = hp_l[row][jj];
            const float xz = xp_l[row][64 + jj],  hz = hp_l[row][64 + jj];
            const float xn = xp_l[row][128 + jj], hn = hp_l[row][128 + jj];
            const float ar = xr + hr + bih[gj] + bhh[gj];
            const float az = xz + hz + bih[1024 + gj] + bhh[1024 + gj];
            const float rg = 1.f / (1.f + __expf(-ar));
            const float zg = 1.f / (1.f + __expf(-az));
            const float nc = tanhf(xn + bih[2048 + gj] + rg * (hn + bhh[2048 + gj]));
            const float hold = hf[(size_t)cur * (NBATCH * HDIM) + (size_t)nIdx * HDIM + gj];
            const float hnew = (1.f - zg) * nc + zg * hold;
            out[((size_t)t * NBATCH + nIdx) * HDIM + gj] = hnew;
            if (t == TSTEPS - 1) {
                out[(size_t)TSTEPS * NBATCH * HDIM + (size_t)nIdx * HDIM + gj] = hnew;
            } else {
                const float m  = mask_val(masks, mfmt, (t + 1) * NBATCH + nIdx);
                const float hm = hnew * m;
                const size_t ho = (size_t)nxt * (NBATCH * HDIM) + (size_t)nIdx * HDIM + gj;
                hf[ho] = hm;
                const unsigned short hi = f2bf(hm);
                hhi[ho] = hi;
                hlo[ho] = f2bf(hm - bf2f(hi));
            }
        }

        if (t != TSTEPS - 1) {
            __syncthreads();
            if (tid == 0) {
                __threadfence();
                int a = __hip_atomic_fetch_add(bar_ctr, 1, __ATOMIC_ACQ_REL, SCOPE_AGENT);
                if (a == (int)gridDim.x - 1) {
                    __hip_atomic_store(bar_ctr, 0, __ATOMIC_RELAXED, SCOPE_AGENT);
                    __hip_atomic_store(bar_gen, t + 1, __ATOMIC_RELEASE, SCOPE_AGENT);
                } else {
                    while (__hip_atomic_load(bar_gen, __ATOMIC_ACQUIRE, SCOPE_AGENT) < t + 1) {
                        __builtin_amdgcn_s_sleep(16);
                    }
                }
            }
            __syncthreads();
        }
    }
}

extern "C" void kernel_launch(void* const* d_in, const int* in_sizes, int n_in,
                              void* d_out, int out_size, void* d_ws, size_t ws_size,
                              hipStream_t stream) {
    const float* x      = (const float*)d_in[0];
    const float* hidden = (const float*)d_in[1];
    const unsigned char* masks = (const unsigned char*)d_in[2];
    const float* wih    = (const float*)d_in[3];
    const float* whh    = (const float*)d_in[4];
    const float* bih    = (const float*)d_in[5];
    const float* bhh    = (const float*)d_in[6];
    float* out = (float*)d_out;
    char*  ws  = (char*)d_ws;

    hipMemsetAsync(ws, 0, 4096, stream);
    detect_mask<<<1, 256, 0, stream>>>(masks, (int*)(ws + MFLAG_OFF));
    conv_w<<<3072, 256, 0, stream>>>(wih, whh,
                                     (unsigned short*)(ws + WIH_OFF),
                                     (unsigned short*)(ws + WHH_OFF));
    init_h<<<128, 256, 0, stream>>>(hidden, masks, (const int*)(ws + MFLAG_OFF),
                                    (float*)(ws + HF_OFF),
                                    (unsigned short*)(ws + HHI_OFF),
                                    (unsigned short*)(ws + HLO_OFF));

    if (ws_size >= (size_t)WS_NEED) {
        gru_seq<<<256, 512, 0, stream>>>(x, masks,
                                         (const int*)(ws + MFLAG_OFF),
                                         bih, bhh,
                                         (const unsigned short*)(ws + WIH_OFF),
                                         (const unsigned short*)(ws + WHH_OFF),
                                         hidden, out,
                                         (unsigned short*)(ws + HHI_OFF),
                                         (unsigned short*)(ws + HLO_OFF),
                                         (unsigned*)(ws + CTR_OFF));
    } else {
        gru_main<<<64, 256, 0, stream>>>(x, masks, bih, bhh,
                                         (const unsigned short*)(ws + WIH_OFF),
                                         (const unsigned short*)(ws + WHH_OFF),
                                         out,
                                         (float*)(ws + HF_OFF),
                                         (unsigned short*)(ws + HHI_OFF),
                                         (unsigned short*)(ws + HLO_OFF),
                                         (int*)(ws + BAR_CTR_OFF), (int*)(ws + BAR_GEN_OFF),
                                         (const int*)(ws + MFLAG_OFF));
    }
}

// Round 6
// 5178.936 us; speedup vs baseline: 1.0506x; 1.0506x over previous
//
#include <hip/hip_runtime.h>

// Masked GRU (RNNStateEncoder), T=256, N=128, D=H=1024.
// Persistent step kernel: 256 WGs x 512 threads (8 waves), WG = 32 rows x 16 h-cols.
// Round-6 change: h carried as packed u32 (hi|lo bf16) through DEVICE-SCOPE
// (sc1) atomics -> h never lives in L2 -> no acquire-invalidate, no wbl2 work.
// W_ih/x/masks stay L2-resident across all 256 steps. Barrier = per-WG flag
// release-store + wave-parallel relaxed polls (no RMW contention, no inv).
// Fallback (ws too small): round-2 monolithic persistent kernel.

#define TSTEPS 256
#define NBATCH 128
#define DDIM   1024
#define HDIM   1024

typedef short  bf16x8 __attribute__((ext_vector_type(8)));
typedef float  f32x4  __attribute__((ext_vector_type(4)));
typedef unsigned long long ull;

// ---- ws layout (bytes) ----
#define BAR_CTR_OFF  0                          // fallback
#define BAR_GEN_OFF  4                          // fallback
#define MFLAG_OFF    2048
#define FLAGS_OFF    8192                       // 256 flags x 64B spacing = 16KB
#define WIH_OFF      32768
#define WHH_OFF      (WIH_OFF + 6291456)        // 6324224
#define HP_OFF       (WHH_OFF + 6291456)        // 12615680 : u32 hp[2][128*1024]
#define HHI_OFF      (HP_OFF + 1048576)         // 13664256 : fallback
#define HLO_OFF      (HHI_OFF + 524288)         // 14188544 : fallback
#define HF_OFF       (HLO_OFF + 524288)         // 14712832 : fallback
#define WS_NEED      (HF_OFF + 1048576ull)      // ~15.8 MB

#define SCOPE_AGENT __HIP_MEMORY_SCOPE_AGENT

__device__ __forceinline__ unsigned short f2bf(float f) {
    union { float f; unsigned u; } v; v.f = f;
    unsigned r = v.u + 0x7FFFu + ((v.u >> 16) & 1u);   // RNE
    return (unsigned short)(r >> 16);
}
__device__ __forceinline__ float bf2f(unsigned short h) {
    union { unsigned u; float f; } v; v.u = ((unsigned)h) << 16;
    return v.f;
}

__device__ __forceinline__ float mask_val(const void* m, int fmt, int idx) {
    if (fmt == 0) return ((const unsigned char*)m)[idx] ? 1.f : 0.f;
    if (fmt == 1) return ((const int*)m)[idx] ? 1.f : 0.f;
    return (((const float*)m)[idx] != 0.f) ? 1.f : 0.f;
}

// device-scope (sc1) accessors: bypass L2, coherent at L3 without inv/wbl2
__device__ __forceinline__ ull ld_dev64(const ull* p) {
    return __hip_atomic_load(p, __ATOMIC_RELAXED, SCOPE_AGENT);
}
__device__ __forceinline__ void st_dev32(unsigned* p, unsigned v) {
    __hip_atomic_store(p, v, __ATOMIC_RELAXED, SCOPE_AGENT);
}

// ---- detect mask dtype: 0 = bool bytes, 1 = int32, 2 = float32 ----
__global__ void detect_mask(const unsigned char* __restrict__ m8, int* __restrict__ flag) {
    __shared__ int s_ones, s_c01, s_cf;
    if (threadIdx.x == 0) { s_ones = 0; s_c01 = 0; s_cf = 0; }
    __syncthreads();
    int ones = 0;
    for (int i = threadIdx.x; i < 4096; i += 256) ones += (m8[i] == 1);
    int c01 = 0, cf = 0;
    const unsigned* m32 = (const unsigned*)m8;
    for (int i = threadIdx.x; i < 1024; i += 256) {
        unsigned v = m32[i];
        c01 += (v <= 1u);
        cf  += (v == 0u || v == 0x3F800000u);
    }
    atomicAdd(&s_ones, ones); atomicAdd(&s_c01, c01); atomicAdd(&s_cf, cf);
    __syncthreads();
    if (threadIdx.x == 0) *flag = (s_ones > 2048) ? 0 : ((s_c01 >= s_cf) ? 1 : 2);
}

// ---- convert both weight matrices to bf16 (row-major (3072,1024)) ----
__global__ void conv_w(const float* __restrict__ wih, const float* __restrict__ whh,
                       unsigned short* __restrict__ wih_b, unsigned short* __restrict__ whh_b) {
    size_t i = ((size_t)blockIdx.x * 256 + threadIdx.x) * 4;
    if (i >= (size_t)3145728) return;
    float4 a = *(const float4*)(wih + i);
    ushort4 ra; ra.x = f2bf(a.x); ra.y = f2bf(a.y); ra.z = f2bf(a.z); ra.w = f2bf(a.w);
    *(ushort4*)(wih_b + i) = ra;
    float4 b = *(const float4*)(whh + i);
    ushort4 rb; rb.x = f2bf(b.x); rb.y = f2bf(b.y); rb.z = f2bf(b.z); rb.w = f2bf(b.w);
    *(ushort4*)(whh_b + i) = rb;
}

// ---- init h0 (pre-masked with m[0]) ----
__global__ void init_h(const float* __restrict__ h0, const unsigned char* __restrict__ masks,
                       const int* __restrict__ flag,
                       float* __restrict__ hf, unsigned short* __restrict__ hhi,
                       unsigned short* __restrict__ hlo, unsigned* __restrict__ hp) {
    int i = (blockIdx.x * 256 + threadIdx.x) * 4;
    if (i >= NBATCH * HDIM) return;
    int fmt = *flag;
    int n = i >> 10;
    float m = mask_val(masks, fmt, n);
    float4 a = *(const float4*)(h0 + i);
    float v[4] = { a.x * m, a.y * m, a.z * m, a.w * m };
#pragma unroll
    for (int q = 0; q < 4; ++q) {
        hf[i + q] = v[q];
        unsigned short hi = f2bf(v[q]);
        unsigned short lo = f2bf(v[q] - bf2f(hi));
        hhi[i + q] = hi;
        hlo[i + q] = lo;
        hp[i + q] = ((unsigned)hi << 16) | (unsigned)lo;
    }
}

// ============== main persistent GRU kernel: 256 WGs x 512 threads ==============
__launch_bounds__(512, 2)
__global__ void gru_seq(const float* __restrict__ x,
                        const unsigned char* __restrict__ masks,
                        const int* __restrict__ mflag,
                        const float* __restrict__ bih,
                        const float* __restrict__ bhh,
                        const unsigned short* __restrict__ wih,
                        const unsigned short* __restrict__ whh,
                        const float* __restrict__ h0,
                        float* __restrict__ out,
                        unsigned* __restrict__ hp,
                        unsigned* __restrict__ flags) {
    const int bid  = blockIdx.x;
    const int cb   = bid >> 2;          // 0..63 : 16 h-cols
    const int rb   = bid & 3;           // 0..3  : 32 batch rows; barrier group
    const int tid  = threadIdx.x;
    const int wave = tid >> 6;          // 0..7
    const int lane = tid & 63;
    const int l15  = lane & 15;
    const int l4   = lane >> 4;
    const int rt   = wave >> 2;         // row-tile 0..1
    const int kq   = wave & 3;          // K quarter 0..3
    const int mfmt = *mflag;
    const int an   = rb * 32 + rt * 16 + l15;    // A-fragment batch row

    __shared__ __align__(16) unsigned short Wl[49152];  // W_hh slice 48x1024, swizzled
    __shared__ __align__(16) f32x4 Pl[1536];            // 8 waves x 64 lanes x 3 ct
    float* Plf = (float*)Pl;

    // ---- stage W_hh slice into LDS (cacheable reads; L2-resident) ----
#pragma unroll
    for (int it = 0; it < 12; ++it) {
        const int ck = it * 512 + tid;          // 16B chunks
        const int sr = ck >> 7;                 // 0..47
        const int kc = ck & 127;
        const int grow = (sr >> 4) * 1024 + cb * 16 + (sr & 15);
        bf16x8 v = *(const bf16x8*)(whh + (size_t)grow * 1024 + kc * 8);
        const int byte = (sr * 2048 + kc * 16) ^ ((sr & 7) << 4);
        *(bf16x8*)((char*)Wl + byte) = v;
    }

    // ---- per-thread output mapping: 1 (row, col) each ----
    const int r = tid >> 4, c = tid & 15;
    const int n = rb * 32 + r;
    const int j = cb * 16 + c;
    const int rtp = r >> 4, ip = r & 3;
    const int lanep = ((r >> 2) & 3) * 16 + c;
    const float bir = bih[j], biz = bih[1024 + j], bin = bih[2048 + j];
    const float bhr = bhh[j], bhz = bhh[1024 + j], bhn = bhh[2048 + j];

    float hold = h0[(size_t)n * 1024 + j] * mask_val(masks, mfmt, n);
    float mn   = mask_val(masks, mfmt, NBATCH + n);     // mask[t=1]

    unsigned* myflag = flags + (rb * 64 + cb) * 16;     // 64B spacing
    unsigned* pollfl = flags + (rb * 64 + lane) * 16;   // wave0 lane -> one WG's flag

    const f32x4 zz = {0.f, 0.f, 0.f, 0.f};

    // xp GEMM for time tt (own slice, in registers; cacheable x/W_ih)
    auto xp_compute = [&](int tt, f32x4* axx) {
        axx[0] = zz; axx[1] = zz; axx[2] = zz;
        const float* xrow = x + ((size_t)tt * NBATCH + an) * 1024 + kq * 256 + l4 * 8;
#pragma unroll
        for (int kt = 0; kt < 8; ++kt) {
            float4 u0 = *(const float4*)(xrow + kt * 32);
            float4 u1 = *(const float4*)(xrow + kt * 32 + 4);
            bf16x8 a;
            a[0] = (short)f2bf(u0.x); a[1] = (short)f2bf(u0.y);
            a[2] = (short)f2bf(u0.z); a[3] = (short)f2bf(u0.w);
            a[4] = (short)f2bf(u1.x); a[5] = (short)f2bf(u1.y);
            a[6] = (short)f2bf(u1.z); a[7] = (short)f2bf(u1.w);
#pragma unroll
            for (int ct = 0; ct < 3; ++ct) {
                const bf16x8 bw = *(const bf16x8*)(wih +
                    (size_t)(ct * 1024 + cb * 16 + l15) * 1024 + kq * 256 + kt * 32 + l4 * 8);
                axx[ct] = __builtin_amdgcn_mfma_f32_16x16x32_bf16(a, bw, axx[ct], 0, 0, 0);
            }
        }
    };
    auto redx = [&](int ct) -> float {
        float s = 0.f;
#pragma unroll
        for (int q = 0; q < 4; ++q)
            s += Plf[((((rtp * 4 + q) * 64 + lanep) * 3 + ct) << 2) + ip];
        return s;
    };

    // ---- prologue: xp[0] ----
    f32x4 axx[3];
    xp_compute(0, axx);
#pragma unroll
    for (int ct = 0; ct < 3; ++ct) Pl[(wave * 64 + lane) * 3 + ct] = axx[ct];
    __syncthreads();
    float xr  = redx(0) + bir;
    float xz  = redx(1) + biz;
    float xn_ = redx(2) + bin;
    __syncthreads();

    for (int t = 0; t < TSTEPS; ++t) {
        const int cur = t & 1, nxt = cur ^ 1;
        const unsigned* hp_c = hp + (size_t)cur * (NBATCH * HDIM);
        unsigned*       hp_n = hp + (size_t)nxt * (NBATCH * HDIM);

        // issue all h loads (device-scope, bypass L2 -> always fresh, no inv needed)
        ull q[8][4];
        {
            const ull* hq = (const ull*)(hp_c + (size_t)an * 1024) + kq * 128 + l4 * 4;
#pragma unroll
            for (int kt = 0; kt < 8; ++kt) {
                const ull* p = hq + kt * 16;
                q[kt][0] = ld_dev64(p);     q[kt][1] = ld_dev64(p + 1);
                q[kt][2] = ld_dev64(p + 2); q[kt][3] = ld_dev64(p + 3);
            }
        }

        // xp[t+1] overlaps h-load L3 latency
        if (t < TSTEPS - 1) xp_compute(t + 1, axx);

        // h MFMAs (unpack packed hi|lo in regs)
        f32x4 acch[3]; acch[0] = zz; acch[1] = zz; acch[2] = zz;
#pragma unroll
        for (int kt = 0; kt < 8; ++kt) {
            unsigned e[8];
            e[0] = (unsigned)q[kt][0]; e[1] = (unsigned)(q[kt][0] >> 32);
            e[2] = (unsigned)q[kt][1]; e[3] = (unsigned)(q[kt][1] >> 32);
            e[4] = (unsigned)q[kt][2]; e[5] = (unsigned)(q[kt][2] >> 32);
            e[6] = (unsigned)q[kt][3]; e[7] = (unsigned)(q[kt][3] >> 32);
            bf16x8 ah, al;
#pragma unroll
            for (int i = 0; i < 8; ++i) {
                ah[i] = (short)(e[i] >> 16);
                al[i] = (short)(e[i] & 0xFFFFu);
            }
            const int ktg = kq * 8 + kt;
#pragma unroll
            for (int ct = 0; ct < 3; ++ct) {
                const int sr = ct * 16 + l15;
                const int byte = (sr * 2048 + ktg * 64 + l4 * 16) ^ ((sr & 7) << 4);
                const bf16x8 bw = *(const bf16x8*)((char*)Wl + byte);
                acch[ct] = __builtin_amdgcn_mfma_f32_16x16x32_bf16(ah, bw, acch[ct], 0, 0, 0);
                acch[ct] = __builtin_amdgcn_mfma_f32_16x16x32_bf16(al, bw, acch[ct], 0, 0, 0);
            }
        }
#pragma unroll
        for (int ct = 0; ct < 3; ++ct) Pl[(wave * 64 + lane) * 3 + ct] = acch[ct];
        __syncthreads();                                        // #1: h partials ready

        // gates: 1 output per thread
        const float hr = redx(0) + bhr;
        const float hz = redx(1) + bhz;
        const float hn = redx(2) + bhn;
        const float rg = 1.f / (1.f + __expf(-(xr + hr)));
        const float zg = 1.f / (1.f + __expf(-(xz + hz)));
        const float nc = tanhf(xn_ + rg * hn);
        const float hnew = (1.f - zg) * nc + zg * hold;
        __builtin_nontemporal_store(hnew, &out[((size_t)t * NBATCH + n) * HDIM + j]);

        if (t == TSTEPS - 1) {
            __builtin_nontemporal_store(hnew,
                &out[(size_t)TSTEPS * NBATCH * HDIM + (size_t)n * HDIM + j]);
        } else {
            const float hm = hnew * mn;
            hold = hm;
            const unsigned short hi = f2bf(hm);
            const unsigned short lo = f2bf(hm - bf2f(hi));
            st_dev32(&hp_n[(size_t)n * 1024 + j], ((unsigned)hi << 16) | (unsigned)lo);

            // drain this wave's h stores to L3, then group barrier arrival
            asm volatile("s_waitcnt vmcnt(0)" ::: "memory");
            __syncthreads();                                    // #2 (+compiler waitcnt/wave)
            if (tid == 0)
                __hip_atomic_store(myflag, (unsigned)(t + 1), __ATOMIC_RELEASE, SCOPE_AGENT);

            // xp reduce overlaps other WGs' progress
#pragma unroll
            for (int ct = 0; ct < 3; ++ct) Pl[(wave * 64 + lane) * 3 + ct] = axx[ct];
            __syncthreads();                                    // #3: xp partials ready
            xr  = redx(0) + bir;
            xz  = redx(1) + biz;
            xn_ = redx(2) + bin;
            mn  = (t + 2 < TSTEPS) ? mask_val(masks, mfmt, (t + 2) * NBATCH + n) : 0.f;

            // wave-parallel poll: lane L watches WG L of this rb-group (no inv!)
            if (wave == 0) {
                const unsigned tgt = (unsigned)(t + 1);
                while (true) {
                    unsigned v = __hip_atomic_load(pollfl, __ATOMIC_RELAXED, SCOPE_AGENT);
                    if (__all((int)(v >= tgt))) break;
                    __builtin_amdgcn_s_sleep(1);
                }
            }
            __syncthreads();                                    // #4: h[t+1] visible
        }
    }
}

// ============== Fallback: round-2 monolithic kernel (ws too small) ==============
__launch_bounds__(256)
__global__ void gru_main(const float* __restrict__ x,
                         const unsigned char* __restrict__ masks,
                         const float* __restrict__ bih, const float* __restrict__ bhh,
                         const unsigned short* __restrict__ wih,
                         const unsigned short* __restrict__ whh,
                         float* __restrict__ out,
                         float* __restrict__ hf,
                         unsigned short* __restrict__ hhi,
                         unsigned short* __restrict__ hlo,
                         int* __restrict__ bar_ctr, int* __restrict__ bar_gen,
                         const int* __restrict__ mflag) {
    const int bid  = blockIdx.x;
    const int xcd  = bid & 7;
    const int slot = bid >> 3;
    const int cb   = xcd * 2 + (slot >> 2);
    const int rb   = slot & 3;
    const int tid  = threadIdx.x;
    const int wid  = tid >> 6;
    const int lane = tid & 63;
    const int l15  = lane & 15;
    const int l4   = lane >> 4;
    const int mfmt = *mflag;

    __shared__ float xp_l[32][196];
    __shared__ float hp_l[32][196];

    int gbase[3];
#pragma unroll
    for (int c = 0; c < 3; ++c) {
        int ct = wid * 3 + c;
        gbase[c] = (ct >> 2) * 1024 + cb * 64 + (ct & 3) * 16;
    }

    for (int t = 0; t < TSTEPS; ++t) {
        const int cur = t & 1, nxt = cur ^ 1;
        f32x4 accx[2][3], acch[2][3];
        const f32x4 zz = {0.f, 0.f, 0.f, 0.f};
#pragma unroll
        for (int rt = 0; rt < 2; ++rt)
#pragma unroll
            for (int c = 0; c < 3; ++c) { accx[rt][c] = zz; acch[rt][c] = zz; }

        const unsigned short* hhi_c = hhi + (size_t)cur * (NBATCH * HDIM);
        const unsigned short* hlo_c = hlo + (size_t)cur * (NBATCH * HDIM);

        for (int kk = 0; kk < DDIM; kk += 32) {
            const int kb = kk + l4 * 8;
            bf16x8 axh[2], axl[2], ahh[2], ahl[2];
#pragma unroll
            for (int rt = 0; rt < 2; ++rt) {
                const int row = rb * 32 + rt * 16 + l15;
                const float* px = x + ((size_t)(t * NBATCH + row)) * DDIM + kb;
                float4 f0 = *(const float4*)px;
                float4 f1 = *(const float4*)(px + 4);
                float v[8] = { f0.x, f0.y, f0.z, f0.w, f1.x, f1.y, f1.z, f1.w };
#pragma unroll
                for (int qq = 0; qq < 8; ++qq) {
                    unsigned short hi = f2bf(v[qq]);
                    axh[rt][qq] = (short)hi;
                    axl[rt][qq] = (short)f2bf(v[qq] - bf2f(hi));
                }
                const size_t hoff = (size_t)row * HDIM + kb;
                ahh[rt] = *(const bf16x8*)(hhi_c + hoff);
                ahl[rt] = *(const bf16x8*)(hlo_c + hoff);
            }
#pragma unroll
            for (int c = 0; c < 3; ++c) {
                const size_t wrow = (size_t)(gbase[c] + l15) * 1024 + kb;
                const bf16x8 bx = *(const bf16x8*)(wih + wrow);
                const bf16x8 bh = *(const bf16x8*)(whh + wrow);
#pragma unroll
                for (int rt = 0; rt < 2; ++rt) {
                    accx[rt][c] = __builtin_amdgcn_mfma_f32_16x16x32_bf16(axh[rt], bx, accx[rt][c], 0, 0, 0);
                    accx[rt][c] = __builtin_amdgcn_mfma_f32_16x16x32_bf16(axl[rt], bx, accx[rt][c], 0, 0, 0);
                    acch[rt][c] = __builtin_amdgcn_mfma_f32_16x16x32_bf16(ahh[rt], bh, acch[rt][c], 0, 0, 0);
                    acch[rt][c] = __builtin_amdgcn_mfma_f32_16x16x32_bf16(ahl[rt], bh, acch[rt][c], 0, 0, 0);
                }
            }
        }

#pragma unroll
        for (int c = 0; c < 3; ++c) {
            const int ct = wid * 3 + c;
#pragma unroll
            for (int rt = 0; rt < 2; ++rt) {
#pragma unroll
                for (int i = 0; i < 4; ++i) {
                    const int row = rt * 16 + l4 * 4 + i;
                    const int col = ct * 16 + l15;
                    xp_l[row][col] = accx[rt][c][i];
                    hp_l[row][col] = acch[rt][c][i];
                }
            }
        }
        __syncthreads();

#pragma unroll
        for (int u = 0; u < 8; ++u) {
            const int o   = u * 256 + tid;
            const int row = o >> 6;
            const int jj  = o & 63;
            const int nIdx = rb * 32 + row;
            const int gj   = cb * 64 + jj;
            const float xr = xp_l[row][jj],       hr = hp_l[row][jj];
            const float xz = xp_l[row][64 + jj],  hz = hp_l[row][64 + jj];
            const float xn = xp_l[row][128 + jj], hn = hp_l[row][128 + jj];
            const float ar = xr + hr + bih[gj] + bhh[gj];
            const float az = xz + hz + bih[1024 + gj] + bhh[1024 + gj];
            const float rg = 1.f / (1.f + __expf(-ar));
            const float zg = 1.f / (1.f + __expf(-az));
            const float nc = tanhf(xn + bih[2048 + gj] + rg * (hn + bhh[2048 + gj]));
            const float hold = hf[(size_t)cur * (NBATCH * HDIM) + (size_t)nIdx * HDIM + gj];
            const float hnew = (1.f - zg) * nc + zg * hold;
            out[((size_t)t * NBATCH + nIdx) * HDIM + gj] = hnew;
            if (t == TSTEPS - 1) {
                out[(size_t)TSTEPS * NBATCH * HDIM + (size_t)nIdx * HDIM + gj] = hnew;
            } else {
                const float m  = mask_val(masks, mfmt, (t + 1) * NBATCH + nIdx);
                const float hm = hnew * m;
                const size_t ho = (size_t)nxt * (NBATCH * HDIM) + (size_t)nIdx * HDIM + gj;
                hf[ho] = hm;
                const unsigned short hi = f2bf(hm);
                hhi[ho] = hi;
                hlo[ho] = f2bf(hm - bf2f(hi));
            }
        }

        if (t != TSTEPS - 1) {
            __syncthreads();
            if (tid == 0) {
                __threadfence();
                int a = __hip_atomic_fetch_add(bar_ctr, 1, __ATOMIC_ACQ_REL, SCOPE_AGENT);
                if (a == (int)gridDim.x - 1) {
                    __hip_atomic_store(bar_ctr, 0, __ATOMIC_RELAXED, SCOPE_AGENT);
                    __hip_atomic_store(bar_gen, t + 1, __ATOMIC_RELEASE, SCOPE_AGENT);
                } else {
                    while (__hip_atomic_load(bar_gen, __ATOMIC_ACQUIRE, SCOPE_AGENT) < t + 1) {
                        __builtin_amdgcn_s_sleep(16);
                    }
                }
            }
            __syncthreads();
        }
    }
}

extern "C" void kernel_launch(void* const* d_in, const int* in_sizes, int n_in,
                              void* d_out, int out_size, void* d_ws, size_t ws_size,
                              hipStream_t stream) {
    const float* x      = (const float*)d_in[0];
    const float* hidden = (const float*)d_in[1];
    const unsigned char* masks = (const unsigned char*)d_in[2];
    const float* wih    = (const float*)d_in[3];
    const float* whh    = (const float*)d_in[4];
    const float* bih    = (const float*)d_in[5];
    const float* bhh    = (const float*)d_in[6];
    float* out = (float*)d_out;
    char*  ws  = (char*)d_ws;

    hipMemsetAsync(ws, 0, 32768, stream);
    detect_mask<<<1, 256, 0, stream>>>(masks, (int*)(ws + MFLAG_OFF));
    conv_w<<<3072, 256, 0, stream>>>(wih, whh,
                                     (unsigned short*)(ws + WIH_OFF),
                                     (unsigned short*)(ws + WHH_OFF));
    init_h<<<128, 256, 0, stream>>>(hidden, masks, (const int*)(ws + MFLAG_OFF),
                                    (float*)(ws + HF_OFF),
                                    (unsigned short*)(ws + HHI_OFF),
                                    (unsigned short*)(ws + HLO_OFF),
                                    (unsigned*)(ws + HP_OFF));

    if (ws_size >= (size_t)WS_NEED) {
        gru_seq<<<256, 512, 0, stream>>>(x, masks,
                                         (const int*)(ws + MFLAG_OFF),
                                         bih, bhh,
                                         (const unsigned short*)(ws + WIH_OFF),
                                         (const unsigned short*)(ws + WHH_OFF),
                                         hidden, out,
                                         (unsigned*)(ws + HP_OFF),
                                         (unsigned*)(ws + FLAGS_OFF));
    } else {
        gru_main<<<64, 256, 0, stream>>>(x, masks, bih, bhh,
                                         (const unsigned short*)(ws + WIH_OFF),
                                         (const unsigned short*)(ws + WHH_OFF),
                                         out,
                                         (float*)(ws + HF_OFF),
                                         (unsigned short*)(ws + HHI_OFF),
                                         (unsigned short*)(ws + HLO_OFF),
                                         (int*)(ws + BAR_CTR_OFF), (int*)(ws + BAR_GEN_OFF),
                                         (const int*)(ws + MFLAG_OFF));
    }
}

// Round 7
// 3818.074 us; speedup vs baseline: 1.4251x; 1.3564x over previous
//
#include <hip/hip_runtime.h>

// Masked GRU (RNNStateEncoder), T=256, N=128, D=H=1024.
// Persistent step kernel: 256 WGs x 512 threads, WG = 32 rows x 16 h-cols.
// Round-7: h exchange via ROTATING PER-STEP BUFFERS:
//   - writes: sc1 u32 (straight to L3, no dirty L2, no wbl2)
//   - reads:  PLAIN dwordx4 (coalesced, L2-cached broadcast) - fresh addresses
//     each step so no stale-line hazard, no acquire-invalidate ever.
//   - barrier: s_waitcnt vmcnt(0) + relaxed sc1 flag store; wave-parallel poll.
//   - XCD-aware bid remap: 4 rb-partners of a cb share one XCD (W_ih L2-res).
// Fallback (ws too small): round-2 monolithic persistent kernel.

#define TSTEPS 256
#define NBATCH 128
#define DDIM   1024
#define HDIM   1024

typedef short  bf16x8 __attribute__((ext_vector_type(8)));
typedef float  f32x4  __attribute__((ext_vector_type(4)));
typedef unsigned long long ull;

// ---- ws layout (bytes) ----
#define BAR_CTR_OFF  0                          // fallback
#define BAR_GEN_OFF  4                          // fallback
#define MFLAG_OFF    2048
#define FLAGS_OFF    8192                       // 256 flags x 64B = 16KB
#define WIH_OFF      32768
#define WHH_OFF      (WIH_OFF + 6291456)        // 6324224
#define HF_OFF       (WHH_OFF + 6291456)        // 12615680 (fallback)
#define HHI_OFF      (HF_OFF + 1048576)         // 13664256 (fallback)
#define HLO_OFF      (HHI_OFF + 524288)         // 14188544 (fallback)
#define HP_OFF       (HLO_OFF + 524288)         // 14712832 : u32 hp[257][128*1024]
#define HPBUF        131072ull                  // u32 elements per buffer
#define WS_NEED      (HP_OFF + 257ull * 524288ull)   // ~149.5 MB

#define SCOPE_AGENT __HIP_MEMORY_SCOPE_AGENT

__device__ __forceinline__ unsigned short f2bf(float f) {
    union { float f; unsigned u; } v; v.f = f;
    unsigned r = v.u + 0x7FFFu + ((v.u >> 16) & 1u);   // RNE
    return (unsigned short)(r >> 16);
}
__device__ __forceinline__ float bf2f(unsigned short h) {
    union { unsigned u; float f; } v; v.u = ((unsigned)h) << 16;
    return v.f;
}

__device__ __forceinline__ float mask_val(const void* m, int fmt, int idx) {
    if (fmt == 0) return ((const unsigned char*)m)[idx] ? 1.f : 0.f;
    if (fmt == 1) return ((const int*)m)[idx] ? 1.f : 0.f;
    return (((const float*)m)[idx] != 0.f) ? 1.f : 0.f;
}

__device__ __forceinline__ void st_dev32(unsigned* p, unsigned v) {
    __hip_atomic_store(p, v, __ATOMIC_RELAXED, SCOPE_AGENT);   // sc1, bypass L2
}

// ---- detect mask dtype: 0 = bool bytes, 1 = int32, 2 = float32 ----
__global__ void detect_mask(const unsigned char* __restrict__ m8, int* __restrict__ flag) {
    __shared__ int s_ones, s_c01, s_cf;
    if (threadIdx.x == 0) { s_ones = 0; s_c01 = 0; s_cf = 0; }
    __syncthreads();
    int ones = 0;
    for (int i = threadIdx.x; i < 4096; i += 256) ones += (m8[i] == 1);
    int c01 = 0, cf = 0;
    const unsigned* m32 = (const unsigned*)m8;
    for (int i = threadIdx.x; i < 1024; i += 256) {
        unsigned v = m32[i];
        c01 += (v <= 1u);
        cf  += (v == 0u || v == 0x3F800000u);
    }
    atomicAdd(&s_ones, ones); atomicAdd(&s_c01, c01); atomicAdd(&s_cf, cf);
    __syncthreads();
    if (threadIdx.x == 0) *flag = (s_ones > 2048) ? 0 : ((s_c01 >= s_cf) ? 1 : 2);
}

// ---- convert both weight matrices to bf16 (row-major (3072,1024)) ----
__global__ void conv_w(const float* __restrict__ wih, const float* __restrict__ whh,
                       unsigned short* __restrict__ wih_b, unsigned short* __restrict__ whh_b) {
    size_t i = ((size_t)blockIdx.x * 256 + threadIdx.x) * 4;
    if (i >= (size_t)3145728) return;
    float4 a = *(const float4*)(wih + i);
    ushort4 ra; ra.x = f2bf(a.x); ra.y = f2bf(a.y); ra.z = f2bf(a.z); ra.w = f2bf(a.w);
    *(ushort4*)(wih_b + i) = ra;
    float4 b = *(const float4*)(whh + i);
    ushort4 rb; rb.x = f2bf(b.x); rb.y = f2bf(b.y); rb.z = f2bf(b.z); rb.w = f2bf(b.w);
    *(ushort4*)(whh_b + i) = rb;
}

// ---- init h0 (pre-masked with m[0]) ----
__global__ void init_h(const float* __restrict__ h0, const unsigned char* __restrict__ masks,
                       const int* __restrict__ flag,
                       float* __restrict__ hf, unsigned short* __restrict__ hhi,
                       unsigned short* __restrict__ hlo, unsigned* __restrict__ hp) {
    int i = (blockIdx.x * 256 + threadIdx.x) * 4;
    if (i >= NBATCH * HDIM) return;
    int fmt = *flag;
    int n = i >> 10;
    float m = mask_val(masks, fmt, n);
    float4 a = *(const float4*)(h0 + i);
    float v[4] = { a.x * m, a.y * m, a.z * m, a.w * m };
#pragma unroll
    for (int q = 0; q < 4; ++q) {
        hf[i + q] = v[q];
        unsigned short hi = f2bf(v[q]);
        unsigned short lo = f2bf(v[q] - bf2f(hi));
        hhi[i + q] = hi;
        hlo[i + q] = lo;
        hp[i + q] = ((unsigned)hi << 16) | (unsigned)lo;   // buffer 0
    }
}

// ============== main persistent GRU kernel: 256 WGs x 512 threads ==============
__launch_bounds__(512, 2)
__global__ void gru_seq(const float* __restrict__ x,
                        const unsigned char* __restrict__ masks,
                        const int* __restrict__ mflag,
                        const float* __restrict__ bih,
                        const float* __restrict__ bhh,
                        const unsigned short* __restrict__ wih,
                        const unsigned short* __restrict__ whh,
                        const float* __restrict__ h0,
                        float* __restrict__ out,
                        unsigned* __restrict__ hp,          // 257 rotating buffers
                        unsigned* __restrict__ flags) {
    const int bid  = blockIdx.x;
    // XCD-aware remap: bids {b, b+8, b+16, b+24} (same XCD, round-robin %8)
    // get the SAME cb with rb = 0..3  ->  per-XCD W_ih working set = 8 slices.
    const int cb   = ((bid >> 5) << 3) | (bid & 7);   // 0..63 : 16 h-cols
    const int rb   = (bid >> 3) & 3;                  // 0..3  : 32 batch rows
    const int tid  = threadIdx.x;
    const int wave = tid >> 6;          // 0..7
    const int lane = tid & 63;
    const int l15  = lane & 15;
    const int l4   = lane >> 4;
    const int rt   = wave >> 2;         // row-tile 0..1
    const int kq   = wave & 3;          // K quarter 0..3
    const int mfmt = *mflag;
    const int an   = rb * 32 + rt * 16 + l15;    // A-fragment batch row

    __shared__ __align__(16) unsigned short Wl[49152];  // W_hh slice 48x1024, swizzled
    __shared__ __align__(16) f32x4 Pl[3][512];          // [ct][wave*64+lane] - conflict-free
    float* Plf = (float*)Pl;

    // ---- stage W_hh slice into LDS ----
#pragma unroll
    for (int it = 0; it < 12; ++it) {
        const int ck = it * 512 + tid;          // 16B chunks
        const int sr = ck >> 7;                 // 0..47
        const int kc = ck & 127;
        const int grow = (sr >> 4) * 1024 + cb * 16 + (sr & 15);
        bf16x8 v = *(const bf16x8*)(whh + (size_t)grow * 1024 + kc * 8);
        const int byte = (sr * 2048 + kc * 16) ^ ((sr & 7) << 4);
        *(bf16x8*)((char*)Wl + byte) = v;
    }

    // ---- per-thread output mapping: 1 (row, col) each ----
    const int r = tid >> 4, c = tid & 15;
    const int n = rb * 32 + r;
    const int j = cb * 16 + c;
    const int rtp = r >> 4, ip = r & 3;
    const int lanep = ((r >> 2) & 3) * 16 + c;
    const float bir = bih[j], biz = bih[1024 + j], bin = bih[2048 + j];
    const float bhr = bhh[j], bhz = bhh[1024 + j], bhn = bhh[2048 + j];

    float hold = h0[(size_t)n * 1024 + j] * mask_val(masks, mfmt, n);
    float mn   = mask_val(masks, mfmt, NBATCH + n);     // mask[t=1]

    unsigned* myflag = flags + (rb * 64 + cb) * 16;     // 64B spacing
    unsigned* pollfl = flags + (rb * 64 + lane) * 16;   // wave0 lane -> one WG flag

    const f32x4 zz = {0.f, 0.f, 0.f, 0.f};

    // xp GEMM for time tt (own slice, in registers; x/W_ih L2-cacheable)
    auto xp_compute = [&](int tt, f32x4* axx) {
        axx[0] = zz; axx[1] = zz; axx[2] = zz;
        const float* xrow = x + ((size_t)tt * NBATCH + an) * 1024 + kq * 256 + l4 * 8;
#pragma unroll
        for (int kt = 0; kt < 8; ++kt) {
            float4 u0 = *(const float4*)(xrow + kt * 32);
            float4 u1 = *(const float4*)(xrow + kt * 32 + 4);
            bf16x8 a;
            a[0] = (short)f2bf(u0.x); a[1] = (short)f2bf(u0.y);
            a[2] = (short)f2bf(u0.z); a[3] = (short)f2bf(u0.w);
            a[4] = (short)f2bf(u1.x); a[5] = (short)f2bf(u1.y);
            a[6] = (short)f2bf(u1.z); a[7] = (short)f2bf(u1.w);
#pragma unroll
            for (int ct = 0; ct < 3; ++ct) {
                const bf16x8 bw = *(const bf16x8*)(wih +
                    (size_t)(ct * 1024 + cb * 16 + l15) * 1024 + kq * 256 + kt * 32 + l4 * 8);
                axx[ct] = __builtin_amdgcn_mfma_f32_16x16x32_bf16(a, bw, axx[ct], 0, 0, 0);
            }
        }
    };
    auto redx = [&](int ct) -> float {
        float s = 0.f;
#pragma unroll
        for (int q = 0; q < 4; ++q)
            s += Plf[((ct * 512 + (rtp * 4 + q) * 64 + lanep) << 2) + ip];
        return s;
    };

    // ---- prologue: xp[0] ----
    f32x4 axx[3];
    xp_compute(0, axx);
#pragma unroll
    for (int ct = 0; ct < 3; ++ct) Pl[ct][wave * 64 + lane] = axx[ct];
    __syncthreads();
    float xr  = redx(0) + bir;
    float xz  = redx(1) + biz;
    float xn_ = redx(2) + bin;
    __syncthreads();

    for (int t = 0; t < TSTEPS; ++t) {
        const unsigned* hp_c = hp + (size_t)t * HPBUF;         // read buffer t
        unsigned*       hp_n = hp + (size_t)(t + 1) * HPBUF;   // write buffer t+1

        // coalesced PLAIN loads of h (L2-cached; fresh addresses -> never stale)
        uint4 qa[8], qb[8];
        {
            const uint4* hq = (const uint4*)(hp_c + (size_t)an * 1024 + kq * 256 + l4 * 8);
#pragma unroll
            for (int kt = 0; kt < 8; ++kt) { qa[kt] = hq[kt * 8]; qb[kt] = hq[kt * 8 + 1]; }
        }

        // xp[t+1] overlaps h-load latency
        if (t < TSTEPS - 1) xp_compute(t + 1, axx);

        // h MFMAs (unpack packed hi|lo in regs)
        f32x4 acch[3]; acch[0] = zz; acch[1] = zz; acch[2] = zz;
#pragma unroll
        for (int kt = 0; kt < 8; ++kt) {
            unsigned e[8];
            e[0] = qa[kt].x; e[1] = qa[kt].y; e[2] = qa[kt].z; e[3] = qa[kt].w;
            e[4] = qb[kt].x; e[5] = qb[kt].y; e[6] = qb[kt].z; e[7] = qb[kt].w;
            bf16x8 ah, al;
#pragma unroll
            for (int i = 0; i < 8; ++i) {
                ah[i] = (short)(e[i] >> 16);
                al[i] = (short)(e[i] & 0xFFFFu);
            }
            const int ktg = kq * 8 + kt;
#pragma unroll
            for (int ct = 0; ct < 3; ++ct) {
                const int sr = ct * 16 + l15;
                const int byte = (sr * 2048 + ktg * 64 + l4 * 16) ^ ((sr & 7) << 4);
                const bf16x8 bw = *(const bf16x8*)((char*)Wl + byte);
                acch[ct] = __builtin_amdgcn_mfma_f32_16x16x32_bf16(ah, bw, acch[ct], 0, 0, 0);
                acch[ct] = __builtin_amdgcn_mfma_f32_16x16x32_bf16(al, bw, acch[ct], 0, 0, 0);
            }
        }
#pragma unroll
        for (int ct = 0; ct < 3; ++ct) Pl[ct][wave * 64 + lane] = acch[ct];
        __syncthreads();                                        // #1: h partials ready

        // gates: 1 output per thread
        const float hr = redx(0) + bhr;
        const float hz = redx(1) + bhz;
        const float hn = redx(2) + bhn;
        const float rg = 1.f / (1.f + __expf(-(xr + hr)));
        const float zg = 1.f / (1.f + __expf(-(xz + hz)));
        const float nc = tanhf(xn_ + rg * hn);
        const float hnew = (1.f - zg) * nc + zg * hold;
        __builtin_nontemporal_store(hnew, &out[((size_t)t * NBATCH + n) * HDIM + j]);

        if (t == TSTEPS - 1) {
            __builtin_nontemporal_store(hnew,
                &out[(size_t)TSTEPS * NBATCH * HDIM + (size_t)n * HDIM + j]);
        } else {
            const float hm = hnew * mn;
            hold = hm;
            const unsigned short hi = f2bf(hm);
            const unsigned short lo = f2bf(hm - bf2f(hi));
            st_dev32(&hp_n[(size_t)n * 1024 + j], ((unsigned)hi << 16) | (unsigned)lo);

            // per-wave drain of sc1 stores to L3, then relaxed flag (no wbl2!)
            asm volatile("s_waitcnt vmcnt(0)" ::: "memory");
            __syncthreads();                                    // #2: all waves drained
            if (tid == 0)
                __hip_atomic_store(myflag, (unsigned)(t + 1), __ATOMIC_RELAXED, SCOPE_AGENT);

            // xp reduce overlaps other WGs' progress
#pragma unroll
            for (int ct = 0; ct < 3; ++ct) Pl[ct][wave * 64 + lane] = axx[ct];
            __syncthreads();                                    // #3: xp partials ready
            xr  = redx(0) + bir;
            xz  = redx(1) + biz;
            xn_ = redx(2) + bin;
            mn  = (t + 2 < TSTEPS) ? mask_val(masks, mfmt, (t + 2) * NBATCH + n) : 0.f;

            // wave-parallel poll: lane L watches WG L of this rb-group
            if (wave == 0) {
                const unsigned tgt = (unsigned)(t + 1);
                while (true) {
                    unsigned v = __hip_atomic_load(pollfl, __ATOMIC_RELAXED, SCOPE_AGENT);
                    if (__all((int)(v >= tgt))) break;
                    __builtin_amdgcn_s_sleep(1);
                }
            }
            asm volatile("" ::: "memory");
            __syncthreads();                                    // #4: h[t+1] visible
        }
    }
}

// ============== Fallback: round-2 monolithic kernel (ws too small) ==============
__launch_bounds__(256)
__global__ void gru_main(const float* __restrict__ x,
                         const unsigned char* __restrict__ masks,
                         const float* __restrict__ bih, const float* __restrict__ bhh,
                         const unsigned short* __restrict__ wih,
                         const unsigned short* __restrict__ whh,
                         float* __restrict__ out,
                         float* __restrict__ hf,
                         unsigned short* __restrict__ hhi,
                         unsigned short* __restrict__ hlo,
                         int* __restrict__ bar_ctr, int* __restrict__ bar_gen,
                         const int* __restrict__ mflag) {
    const int bid  = blockIdx.x;
    const int xcd  = bid & 7;
    const int slot = bid >> 3;
    const int cb   = xcd * 2 + (slot >> 2);
    const int rb   = slot & 3;
    const int tid  = threadIdx.x;
    const int wid  = tid >> 6;
    const int lane = tid & 63;
    const int l15  = lane & 15;
    const int l4   = lane >> 4;
    const int mfmt = *mflag;

    __shared__ float xp_l[32][196];
    __shared__ float hp_l[32][196];

    int gbase[3];
#pragma unroll
    for (int c = 0; c < 3; ++c) {
        int ct = wid * 3 + c;
        gbase[c] = (ct >> 2) * 1024 + cb * 64 + (ct & 3) * 16;
    }

    for (int t = 0; t < TSTEPS; ++t) {
        const int cur = t & 1, nxt = cur ^ 1;
        f32x4 accx[2][3], acch[2][3];
        const f32x4 zz = {0.f, 0.f, 0.f, 0.f};
#pragma unroll
        for (int rt = 0; rt < 2; ++rt)
#pragma unroll
            for (int c = 0; c < 3; ++c) { accx[rt][c] = zz; acch[rt][c] = zz; }

        const unsigned short* hhi_c = hhi + (size_t)cur * (NBATCH * HDIM);
        const unsigned short* hlo_c = hlo + (size_t)cur * (NBATCH * HDIM);

        for (int kk = 0; kk < DDIM; kk += 32) {
            const int kb = kk + l4 * 8;
            bf16x8 axh[2], axl[2], ahh[2], ahl[2];
#pragma unroll
            for (int rt = 0; rt < 2; ++rt) {
                const int row = rb * 32 + rt * 16 + l15;
                const float* px = x + ((size_t)(t * NBATCH + row)) * DDIM + kb;
                float4 f0 = *(const float4*)px;
                float4 f1 = *(const float4*)(px + 4);
                float v[8] = { f0.x, f0.y, f0.z, f0.w, f1.x, f1.y, f1.z, f1.w };
#pragma unroll
                for (int qq = 0; qq < 8; ++qq) {
                    unsigned short hi = f2bf(v[qq]);
                    axh[rt][qq] = (short)hi;
                    axl[rt][qq] = (short)f2bf(v[qq] - bf2f(hi));
                }
                const size_t hoff = (size_t)row * HDIM + kb;
                ahh[rt] = *(const bf16x8*)(hhi_c + hoff);
                ahl[rt] = *(const bf16x8*)(hlo_c + hoff);
            }
#pragma unroll
            for (int c = 0; c < 3; ++c) {
                const size_t wrow = (size_t)(gbase[c] + l15) * 1024 + kb;
                const bf16x8 bx = *(const bf16x8*)(wih + wrow);
                const bf16x8 bh = *(const bf16x8*)(whh + wrow);
#pragma unroll
                for (int rt = 0; rt < 2; ++rt) {
                    accx[rt][c] = __builtin_amdgcn_mfma_f32_16x16x32_bf16(axh[rt], bx, accx[rt][c], 0, 0, 0);
                    accx[rt][c] = __builtin_amdgcn_mfma_f32_16x16x32_bf16(axl[rt], bx, accx[rt][c], 0, 0, 0);
                    acch[rt][c] = __builtin_amdgcn_mfma_f32_16x16x32_bf16(ahh[rt], bh, acch[rt][c], 0, 0, 0);
                    acch[rt][c] = __builtin_amdgcn_mfma_f32_16x16x32_bf16(ahl[rt], bh, acch[rt][c], 0, 0, 0);
                }
            }
        }

#pragma unroll
        for (int c = 0; c < 3; ++c) {
            const int ct = wid * 3 + c;
#pragma unroll
            for (int rt = 0; rt < 2; ++rt) {
#pragma unroll
                for (int i = 0; i < 4; ++i) {
                    const int row = rt * 16 + l4 * 4 + i;
                    const int col = ct * 16 + l15;
                    xp_l[row][col] = accx[rt][c][i];
                    hp_l[row][col] = acch[rt][c][i];
                }
            }
        }
        __syncthreads();

#pragma unroll
        for (int u = 0; u < 8; ++u) {
            const int o   = u * 256 + tid;
            const int row = o >> 6;
            const int jj  = o & 63;
            const int nIdx = rb * 32 + row;
            const int gj   = cb * 64 + jj;
            const float xr = xp_l[row][jj],       hr = hp_l[row][jj];
            const float xz = xp_l[row][64 + jj],  hz = hp_l[row][64 + jj];
            const float xn = xp_l[row][128 + jj], hn = hp_l[row][128 + jj];
            const float ar = xr + hr + bih[gj] + bhh[gj];
            const float az = xz + hz + bih[1024 + gj] + bhh[1024 + gj];
            const float rg = 1.f / (1.f + __expf(-ar));
            const float zg = 1.f / (1.f + __expf(-az));
            const float nc = tanhf(xn + bih[2048 + gj] + rg * (hn + bhh[2048 + gj]));
            const float hold = hf[(size_t)cur * (NBATCH * HDIM) + (size_t)nIdx * HDIM + gj];
            const float hnew = (1.f - zg) * nc + zg * hold;
            out[((size_t)t * NBATCH + nIdx) * HDIM + gj] = hnew;
            if (t == TSTEPS - 1) {
                out[(size_t)TSTEPS * NBATCH * HDIM + (size_t)nIdx * HDIM + gj] = hnew;
            } else {
                const float m  = mask_val(masks, mfmt, (t + 1) * NBATCH + nIdx);
                const float hm = hnew * m;
                const size_t ho = (size_t)nxt * (NBATCH * HDIM) + (size_t)nIdx * HDIM + gj;
                hf[ho] = hm;
                const unsigned short hi = f2bf(hm);
                hhi[ho] = hi;
                hlo[ho] = f2bf(hm - bf2f(hi));
            }
        }

        if (t != TSTEPS - 1) {
            __syncthreads();
            if (tid == 0) {
                __threadfence();
                int a = __hip_atomic_fetch_add(bar_ctr, 1, __ATOMIC_ACQ_REL, SCOPE_AGENT);
                if (a == (int)gridDim.x - 1) {
                    __hip_atomic_store(bar_ctr, 0, __ATOMIC_RELAXED, SCOPE_AGENT);
                    __hip_atomic_store(bar_gen, t + 1, __ATOMIC_RELEASE, SCOPE_AGENT);
                } else {
                    while (__hip_atomic_load(bar_gen, __ATOMIC_ACQUIRE, SCOPE_AGENT) < t + 1) {
                        __builtin_amdgcn_s_sleep(16);
                    }
                }
            }
            __syncthreads();
        }
    }
}

extern "C" void kernel_launch(void* const* d_in, const int* in_sizes, int n_in,
                              void* d_out, int out_size, void* d_ws, size_t ws_size,
                              hipStream_t stream) {
    const float* x      = (const float*)d_in[0];
    const float* hidden = (const float*)d_in[1];
    const unsigned char* masks = (const unsigned char*)d_in[2];
    const float* wih    = (const float*)d_in[3];
    const float* whh    = (const float*)d_in[4];
    const float* bih    = (const float*)d_in[5];
    const float* bhh    = (const float*)d_in[6];
    float* out = (float*)d_out;
    char*  ws  = (char*)d_ws;

    hipMemsetAsync(ws, 0, 32768, stream);
    detect_mask<<<1, 256, 0, stream>>>(masks, (int*)(ws + MFLAG_OFF));
    conv_w<<<3072, 256, 0, stream>>>(wih, whh,
                                     (unsigned short*)(ws + WIH_OFF),
                                     (unsigned short*)(ws + WHH_OFF));
    init_h<<<128, 256, 0, stream>>>(hidden, masks, (const int*)(ws + MFLAG_OFF),
                                    (float*)(ws + HF_OFF),
                                    (unsigned short*)(ws + HHI_OFF),
                                    (unsigned short*)(ws + HLO_OFF),
                                    (unsigned*)(ws + HP_OFF));

    if (ws_size >= (size_t)WS_NEED) {
        gru_seq<<<256, 512, 0, stream>>>(x, masks,
                                         (const int*)(ws + MFLAG_OFF),
                                         bih, bhh,
                                         (const unsigned short*)(ws + WIH_OFF),
                                         (const unsigned short*)(ws + WHH_OFF),
                                         hidden, out,
                                         (unsigned*)(ws + HP_OFF),
                                         (unsigned*)(ws + FLAGS_OFF));
    } else {
        gru_main<<<64, 256, 0, stream>>>(x, masks, bih, bhh,
                                         (const unsigned short*)(ws + WIH_OFF),
                                         (const unsigned short*)(ws + WHH_OFF),
                                         out,
                                         (float*)(ws + HF_OFF),
                                         (unsigned short*)(ws + HHI_OFF),
                                         (unsigned short*)(ws + HLO_OFF),
                                         (int*)(ws + BAR_CTR_OFF), (int*)(ws + BAR_GEN_OFF),
                                         (const int*)(ws + MFLAG_OFF));
    }
}

// Round 9
// 3808.505 us; speedup vs baseline: 1.4287x; 1.0025x over previous
//
#include <hip/hip_runtime.h>

// Masked GRU (RNNStateEncoder), T=256, N=128, D=H=1024.
// Persistent step kernel: 256 WGs x 512 threads, WG = 32 rows x 16 h-cols.
// Round-8 (resubmit after infra failure):
//   (a) h rotation window 128 bufs (64 MB) so L3 holds everything
//       (h misses hit L3 not HBM); (b) out-store moved off the barrier
//       critical path (after flag store); (c) XCD mapping = 16 cb x 2 rb
//       per XCD (halves per-XCD h/x miss traffic, W_ih still L2-resident);
//       (d) Pl partial-sum XOR swizzle (kills 8-way LDS write conflicts).
// h written sc1 (straight to L3, no dirty L2), read as plain coalesced
// dwordx4 from rotating addresses (L2 deterministically cycles in ~8 steps
// << 128-step reuse distance -> no stale-line hazard, no acquire-invalidate).
// Fallback (ws too small): round-2 monolithic persistent kernel.

#define TSTEPS 256
#define NBATCH 128
#define DDIM   1024
#define HDIM   1024
#define HPW    128          // rotation window (buffers)

typedef short  bf16x8 __attribute__((ext_vector_type(8)));
typedef float  f32x4  __attribute__((ext_vector_type(4)));
typedef unsigned long long ull;

// ---- ws layout (bytes) ----
#define BAR_CTR_OFF  0                          // fallback
#define BAR_GEN_OFF  4                          // fallback
#define MFLAG_OFF    2048
#define FLAGS_OFF    8192                       // 256 flags x 64B = 16KB
#define WIH_OFF      32768
#define WHH_OFF      (WIH_OFF + 6291456)        // 6324224
#define HF_OFF       (WHH_OFF + 6291456)        // 12615680 (fallback)
#define HHI_OFF      (HF_OFF + 1048576)         // 13664256 (fallback)
#define HLO_OFF      (HHI_OFF + 524288)         // 14188544 (fallback)
#define HP_OFF       (HLO_OFF + 524288)         // 14712832 : u32 hp[128][128*1024]
#define HPBUF        131072ull                  // u32 elements per buffer
#define WS_NEED      (HP_OFF + (ull)HPW * 524288ull)   // ~82 MB

#define SCOPE_AGENT __HIP_MEMORY_SCOPE_AGENT

__device__ __forceinline__ unsigned short f2bf(float f) {
    union { float f; unsigned u; } v; v.f = f;
    unsigned r = v.u + 0x7FFFu + ((v.u >> 16) & 1u);   // RNE
    return (unsigned short)(r >> 16);
}
__device__ __forceinline__ float bf2f(unsigned short h) {
    union { unsigned u; float f; } v; v.u = ((unsigned)h) << 16;
    return v.f;
}

__device__ __forceinline__ float mask_val(const void* m, int fmt, int idx) {
    if (fmt == 0) return ((const unsigned char*)m)[idx] ? 1.f : 0.f;
    if (fmt == 1) return ((const int*)m)[idx] ? 1.f : 0.f;
    return (((const float*)m)[idx] != 0.f) ? 1.f : 0.f;
}

__device__ __forceinline__ void st_dev32(unsigned* p, unsigned v) {
    __hip_atomic_store(p, v, __ATOMIC_RELAXED, SCOPE_AGENT);   // sc1, bypass L2
}

// ---- detect mask dtype: 0 = bool bytes, 1 = int32, 2 = float32 ----
__global__ void detect_mask(const unsigned char* __restrict__ m8, int* __restrict__ flag) {
    __shared__ int s_ones, s_c01, s_cf;
    if (threadIdx.x == 0) { s_ones = 0; s_c01 = 0; s_cf = 0; }
    __syncthreads();
    int ones = 0;
    for (int i = threadIdx.x; i < 4096; i += 256) ones += (m8[i] == 1);
    int c01 = 0, cf = 0;
    const unsigned* m32 = (const unsigned*)m8;
    for (int i = threadIdx.x; i < 1024; i += 256) {
        unsigned v = m32[i];
        c01 += (v <= 1u);
        cf  += (v == 0u || v == 0x3F800000u);
    }
    atomicAdd(&s_ones, ones); atomicAdd(&s_c01, c01); atomicAdd(&s_cf, cf);
    __syncthreads();
    if (threadIdx.x == 0) *flag = (s_ones > 2048) ? 0 : ((s_c01 >= s_cf) ? 1 : 2);
}

// ---- convert both weight matrices to bf16 (row-major (3072,1024)) ----
__global__ void conv_w(const float* __restrict__ wih, const float* __restrict__ whh,
                       unsigned short* __restrict__ wih_b, unsigned short* __restrict__ whh_b) {
    size_t i = ((size_t)blockIdx.x * 256 + threadIdx.x) * 4;
    if (i >= (size_t)3145728) return;
    float4 a = *(const float4*)(wih + i);
    ushort4 ra; ra.x = f2bf(a.x); ra.y = f2bf(a.y); ra.z = f2bf(a.z); ra.w = f2bf(a.w);
    *(ushort4*)(wih_b + i) = ra;
    float4 b = *(const float4*)(whh + i);
    ushort4 rb; rb.x = f2bf(b.x); rb.y = f2bf(b.y); rb.z = f2bf(b.z); rb.w = f2bf(b.w);
    *(ushort4*)(whh_b + i) = rb;
}

// ---- init h0 (pre-masked with m[0]) ----
__global__ void init_h(const float* __restrict__ h0, const unsigned char* __restrict__ masks,
                       const int* __restrict__ flag,
                       float* __restrict__ hf, unsigned short* __restrict__ hhi,
                       unsigned short* __restrict__ hlo, unsigned* __restrict__ hp) {
    int i = (blockIdx.x * 256 + threadIdx.x) * 4;
    if (i >= NBATCH * HDIM) return;
    int fmt = *flag;
    int n = i >> 10;
    float m = mask_val(masks, fmt, n);
    float4 a = *(const float4*)(h0 + i);
    float v[4] = { a.x * m, a.y * m, a.z * m, a.w * m };
#pragma unroll
    for (int q = 0; q < 4; ++q) {
        hf[i + q] = v[q];
        unsigned short hi = f2bf(v[q]);
        unsigned short lo = f2bf(v[q] - bf2f(hi));
        hhi[i + q] = hi;
        hlo[i + q] = lo;
        hp[i + q] = ((unsigned)hi << 16) | (unsigned)lo;   // buffer 0
    }
}

// ============== main persistent GRU kernel: 256 WGs x 512 threads ==============
__launch_bounds__(512, 2)
__global__ void gru_seq(const float* __restrict__ x,
                        const unsigned char* __restrict__ masks,
                        const int* __restrict__ mflag,
                        const float* __restrict__ bih,
                        const float* __restrict__ bhh,
                        const unsigned short* __restrict__ wih,
                        const unsigned short* __restrict__ whh,
                        const float* __restrict__ h0,
                        float* __restrict__ out,
                        unsigned* __restrict__ hp,          // HPW rotating buffers
                        unsigned* __restrict__ flags) {
    const int bid  = blockIdx.x;
    // XCD mapping (dispatch round-robin bid%8): per XCD -> 16 cb x 2 rb.
    const int x7 = bid & 7;
    const int s5 = bid >> 3;                    // 0..31
    const int cb = ((x7 >> 1) << 4) | (s5 >> 1);   // 0..63 : 16 h-cols
    const int rb = ((x7 & 1) << 1) | (s5 & 1);     // 0..3  : 32 batch rows
    const int tid  = threadIdx.x;
    const int wave = tid >> 6;          // 0..7
    const int lane = tid & 63;
    const int l15  = lane & 15;
    const int l4   = lane >> 4;
    const int rt   = wave >> 2;         // row-tile 0..1
    const int kq   = wave & 3;          // K quarter 0..3
    const int mfmt = *mflag;
    const int an   = rb * 32 + rt * 16 + l15;    // A-fragment batch row

    __shared__ __align__(16) unsigned short Wl[49152];  // W_hh slice 48x1024, swizzled
    __shared__ __align__(16) f32x4 Pl[3][512];          // partials, XOR-swizzled

    // ---- stage W_hh slice into LDS ----
#pragma unroll
    for (int it = 0; it < 12; ++it) {
        const int ck = it * 512 + tid;          // 16B chunks
        const int sr = ck >> 7;                 // 0..47
        const int kc = ck & 127;
        const int grow = (sr >> 4) * 1024 + cb * 16 + (sr & 15);
        bf16x8 v = *(const bf16x8*)(whh + (size_t)grow * 1024 + kc * 8);
        const int byte = (sr * 2048 + kc * 16) ^ ((sr & 7) << 4);
        *(bf16x8*)((char*)Wl + byte) = v;
    }

    // ---- per-thread output mapping: 1 (row, col) each ----
    const int r = tid >> 4, c = tid & 15;
    const int n = rb * 32 + r;
    const int j = cb * 16 + c;
    const int rtp = r >> 4, ip = r & 3;
    const int lanep = ((r >> 2) & 3) * 16 + c;
    const float bir = bih[j], biz = bih[1024 + j], bin = bih[2048 + j];
    const float bhr = bhh[j], bhz = bhh[1024 + j], bhn = bhh[2048 + j];

    float hold = h0[(size_t)n * 1024 + j] * mask_val(masks, mfmt, n);
    float mn   = mask_val(masks, mfmt, NBATCH + n);     // mask[t=1]

    unsigned* myflag = flags + (rb * 64 + cb) * 16;     // 64B spacing
    unsigned* pollfl = flags + (rb * 64 + lane) * 16;   // wave0 lane -> one WG flag

    const f32x4 zz = {0.f, 0.f, 0.f, 0.f};
    const int widx  = wave * 64 + lane;
    const int wbyte = (widx * 16) ^ ((widx & 3) << 5);  // swizzled Pl write offset

    // xp GEMM for time tt (own slice, in registers; x/W_ih L2-cacheable)
    auto xp_compute = [&](int tt, f32x4* axx) {
        axx[0] = zz; axx[1] = zz; axx[2] = zz;
        const float* xrow = x + ((size_t)tt * NBATCH + an) * 1024 + kq * 256 + l4 * 8;
#pragma unroll
        for (int kt = 0; kt < 8; ++kt) {
            float4 u0 = *(const float4*)(xrow + kt * 32);
            float4 u1 = *(const float4*)(xrow + kt * 32 + 4);
            bf16x8 a;
            a[0] = (short)f2bf(u0.x); a[1] = (short)f2bf(u0.y);
            a[2] = (short)f2bf(u0.z); a[3] = (short)f2bf(u0.w);
            a[4] = (short)f2bf(u1.x); a[5] = (short)f2bf(u1.y);
            a[6] = (short)f2bf(u1.z); a[7] = (short)f2bf(u1.w);
#pragma unroll
            for (int ct = 0; ct < 3; ++ct) {
                const bf16x8 bw = *(const bf16x8*)(wih +
                    (size_t)(ct * 1024 + cb * 16 + l15) * 1024 + kq * 256 + kt * 32 + l4 * 8);
                axx[ct] = __builtin_amdgcn_mfma_f32_16x16x32_bf16(a, bw, axx[ct], 0, 0, 0);
            }
        }
    };
    // per-thread 4-way K reduction from swizzled Pl
    auto redx = [&](int ct) -> float {
        float s = 0.f;
#pragma unroll
        for (int q = 0; q < 4; ++q) {
            const int idx  = (rtp * 4 + q) * 64 + lanep;
            const int byte = ((idx * 16) ^ ((idx & 3) << 5)) + ip * 4;
            s += *(const float*)((const char*)Pl + ct * 8192 + byte);
        }
        return s;
    };

    // ---- prologue: xp[0] ----
    f32x4 axx[3];
    xp_compute(0, axx);
#pragma unroll
    for (int ct = 0; ct < 3; ++ct)
        *(f32x4*)((char*)Pl + ct * 8192 + wbyte) = axx[ct];
    __syncthreads();
    float xr  = redx(0) + bir;
    float xz  = redx(1) + biz;
    float xn_ = redx(2) + bin;
    __syncthreads();

    for (int t = 0; t < TSTEPS; ++t) {
        const unsigned* hp_c = hp + (size_t)(t & (HPW - 1)) * HPBUF;         // read h[t]
        unsigned*       hp_n = hp + (size_t)((t + 1) & (HPW - 1)) * HPBUF;   // write h[t+1]

        // coalesced plain loads of h (L2-cached; rotating addresses -> never stale)
        uint4 qa[8], qb[8];
        {
            const uint4* hq = (const uint4*)(hp_c + (size_t)an * 1024 + kq * 256 + l4 * 8);
#pragma unroll
            for (int kt = 0; kt < 8; ++kt) { qa[kt] = hq[kt * 8]; qb[kt] = hq[kt * 8 + 1]; }
        }

        // xp[t+1] overlaps h-load latency
        if (t < TSTEPS - 1) xp_compute(t + 1, axx);

        // h MFMAs (unpack packed hi|lo in regs)
        f32x4 acch[3]; acch[0] = zz; acch[1] = zz; acch[2] = zz;
#pragma unroll
        for (int kt = 0; kt < 8; ++kt) {
            unsigned e[8];
            e[0] = qa[kt].x; e[1] = qa[kt].y; e[2] = qa[kt].z; e[3] = qa[kt].w;
            e[4] = qb[kt].x; e[5] = qb[kt].y; e[6] = qb[kt].z; e[7] = qb[kt].w;
            bf16x8 ah, al;
#pragma unroll
            for (int i = 0; i < 8; ++i) {
                ah[i] = (short)(e[i] >> 16);
                al[i] = (short)(e[i] & 0xFFFFu);
            }
            const int ktg = kq * 8 + kt;
#pragma unroll
            for (int ct = 0; ct < 3; ++ct) {
                const int sr = ct * 16 + l15;
                const int byte = (sr * 2048 + ktg * 64 + l4 * 16) ^ ((sr & 7) << 4);
                const bf16x8 bw = *(const bf16x8*)((char*)Wl + byte);
                acch[ct] = __builtin_amdgcn_mfma_f32_16x16x32_bf16(ah, bw, acch[ct], 0, 0, 0);
                acch[ct] = __builtin_amdgcn_mfma_f32_16x16x32_bf16(al, bw, acch[ct], 0, 0, 0);
            }
        }
#pragma unroll
        for (int ct = 0; ct < 3; ++ct)
            *(f32x4*)((char*)Pl + ct * 8192 + wbyte) = acch[ct];
        __syncthreads();                                        // #1: h partials ready

        // gates: 1 output per thread
        const float hr = redx(0) + bhr;
        const float hz = redx(1) + bhz;
        const float hn = redx(2) + bhn;
        const float rg = 1.f / (1.f + __expf(-(xr + hr)));
        const float zg = 1.f / (1.f + __expf(-(xz + hz)));
        const float nc = tanhf(xn_ + rg * hn);
        const float hnew = (1.f - zg) * nc + zg * hold;

        if (t == TSTEPS - 1) {
            __builtin_nontemporal_store(hnew, &out[((size_t)t * NBATCH + n) * HDIM + j]);
            __builtin_nontemporal_store(hnew,
                &out[(size_t)TSTEPS * NBATCH * HDIM + (size_t)n * HDIM + j]);
        } else {
            const float hm = hnew * mn;
            hold = hm;
            const unsigned short hi = f2bf(hm);
            const unsigned short lo = f2bf(hm - bf2f(hi));
            st_dev32(&hp_n[(size_t)n * 1024 + j], ((unsigned)hi << 16) | (unsigned)lo);

            // drain ONLY the h store (out not yet issued), then flag
            asm volatile("s_waitcnt vmcnt(0)" ::: "memory");
            __syncthreads();                                    // #2: all waves drained
            if (tid == 0)
                __hip_atomic_store(myflag, (unsigned)(t + 1), __ATOMIC_RELAXED, SCOPE_AGENT);

            // out store + xp reduce overlap other WGs' progress
            __builtin_nontemporal_store(hnew, &out[((size_t)t * NBATCH + n) * HDIM + j]);
#pragma unroll
            for (int ct = 0; ct < 3; ++ct)
                *(f32x4*)((char*)Pl + ct * 8192 + wbyte) = axx[ct];
            __syncthreads();                                    // #3: xp partials ready
            xr  = redx(0) + bir;
            xz  = redx(1) + biz;
            xn_ = redx(2) + bin;
            mn  = (t + 2 < TSTEPS) ? mask_val(masks, mfmt, (t + 2) * NBATCH + n) : 0.f;

            // wave-parallel poll: lane L watches WG L of this rb-group
            if (wave == 0) {
                const unsigned tgt = (unsigned)(t + 1);
                while (true) {
                    unsigned v = __hip_atomic_load(pollfl, __ATOMIC_RELAXED, SCOPE_AGENT);
                    if (__all((int)(v >= tgt))) break;
                    __builtin_amdgcn_s_sleep(1);
                }
            }
            asm volatile("" ::: "memory");
            __syncthreads();                                    // #4: h[t+1] visible
        }
    }
}

// ============== Fallback: round-2 monolithic kernel (ws too small) ==============
__launch_bounds__(256)
__global__ void gru_main(const float* __restrict__ x,
                         const unsigned char* __restrict__ masks,
                         const float* __restrict__ bih, const float* __restrict__ bhh,
                         const unsigned short* __restrict__ wih,
                         const unsigned short* __restrict__ whh,
                         float* __restrict__ out,
                         float* __restrict__ hf,
                         unsigned short* __restrict__ hhi,
                         unsigned short* __restrict__ hlo,
                         int* __restrict__ bar_ctr, int* __restrict__ bar_gen,
                         const int* __restrict__ mflag) {
    const int bid  = blockIdx.x;
    const int xcd  = bid & 7;
    const int slot = bid >> 3;
    const int cb   = xcd * 2 + (slot >> 2);
    const int rb   = slot & 3;
    const int tid  = threadIdx.x;
    const int wid  = tid >> 6;
    const int lane = tid & 63;
    const int l15  = lane & 15;
    const int l4   = lane >> 4;
    const int mfmt = *mflag;

    __shared__ float xp_l[32][196];
    __shared__ float hp_l[32][196];

    int gbase[3];
#pragma unroll
    for (int c = 0; c < 3; ++c) {
        int ct = wid * 3 + c;
        gbase[c] = (ct >> 2) * 1024 + cb * 64 + (ct & 3) * 16;
    }

    for (int t = 0; t < TSTEPS; ++t) {
        const int cur = t & 1, nxt = cur ^ 1;
        f32x4 accx[2][3], acch[2][3];
        const f32x4 zz = {0.f, 0.f, 0.f, 0.f};
#pragma unroll
        for (int rt = 0; rt < 2; ++rt)
#pragma unroll
            for (int c = 0; c < 3; ++c) { accx[rt][c] = zz; acch[rt][c] = zz; }

        const unsigned short* hhi_c = hhi + (size_t)cur * (NBATCH * HDIM);
        const unsigned short* hlo_c = hlo + (size_t)cur * (NBATCH * HDIM);

        for (int kk = 0; kk < DDIM; kk += 32) {
            const int kb = kk + l4 * 8;
            bf16x8 axh[2], axl[2], ahh[2], ahl[2];
#pragma unroll
            for (int rt = 0; rt < 2; ++rt) {
                const int row = rb * 32 + rt * 16 + l15;
                const float* px = x + ((size_t)(t * NBATCH + row)) * DDIM + kb;
                float4 f0 = *(const float4*)px;
                float4 f1 = *(const float4*)(px + 4);
                float v[8] = { f0.x, f0.y, f0.z, f0.w, f1.x, f1.y, f1.z, f1.w };
#pragma unroll
                for (int qq = 0; qq < 8; ++qq) {
                    unsigned short hi = f2bf(v[qq]);
                    axh[rt][qq] = (short)hi;
                    axl[rt][qq] = (short)f2bf(v[qq] - bf2f(hi));
                }
                const size_t hoff = (size_t)row * HDIM + kb;
                ahh[rt] = *(const bf16x8*)(hhi_c + hoff);
                ahl[rt] = *(const bf16x8*)(hlo_c + hoff);
            }
#pragma unroll
            for (int c = 0; c < 3; ++c) {
                const size_t wrow = (size_t)(gbase[c] + l15) * 1024 + kb;
                const bf16x8 bx = *(const bf16x8*)(wih + wrow);
                const bf16x8 bh = *(const bf16x8*)(whh + wrow);
#pragma unroll
                for (int rt = 0; rt < 2; ++rt) {
                    accx[rt][c] = __builtin_amdgcn_mfma_f32_16x16x32_bf16(axh[rt], bx, accx[rt][c], 0, 0, 0);
                    accx[rt][c] = __builtin_amdgcn_mfma_f32_16x16x32_bf16(axl[rt], bx, accx[rt][c], 0, 0, 0);
                    acch[rt][c] = __builtin_amdgcn_mfma_f32_16x16x32_bf16(ahh[rt], bh, acch[rt][c], 0, 0, 0);
                    acch[rt][c] = __builtin_amdgcn_mfma_f32_16x16x32_bf16(ahl[rt], bh, acch[rt][c], 0, 0, 0);
                }
            }
        }

#pragma unroll
        for (int c = 0; c < 3; ++c) {
            const int ct = wid * 3 + c;
#pragma unroll
            for (int rt = 0; rt < 2; ++rt) {
#pragma unroll
                for (int i = 0; i < 4; ++i) {
                    const int row = rt * 16 + l4 * 4 + i;
                    const int col = ct * 16 + l15;
                    xp_l[row][col] = accx[rt][c][i];
                    hp_l[row][col] = acch[rt][c][i];
                }
            }
        }
        __syncthreads();

#pragma unroll
        for (int u = 0; u < 8; ++u) {
            const int o   = u * 256 + tid;
            const int row = o >> 6;
            const int jj  = o & 63;
            const int nIdx = rb * 32 + row;
            const int gj   = cb * 64 + jj;
            const float xr = xp_l[row][jj],       hr = hp_l[row][jj];
            const float xz = xp_l[row][64 + jj],  hz = hp_l[row][64 + jj];
            const float xn = xp_l[row][128 + jj], hn = hp_l[row][128 + jj];
            const float ar = xr + hr + bih[gj] + bhh[gj];
            const float az = xz + hz + bih[1024 + gj] + bhh[1024 + gj];
            const float rg = 1.f / (1.f + __expf(-ar));
            const float zg = 1.f / (1.f + __expf(-az));
            const float nc = tanhf(xn + bih[2048 + gj] + rg * (hn + bhh[2048 + gj]));
            const float hold = hf[(size_t)cur * (NBATCH * HDIM) + (size_t)nIdx * HDIM + gj];
            const float hnew = (1.f - zg) * nc + zg * hold;
            out[((size_t)t * NBATCH + nIdx) * HDIM + gj] = hnew;
            if (t == TSTEPS - 1) {
                out[(size_t)TSTEPS * NBATCH * HDIM + (size_t)nIdx * HDIM + gj] = hnew;
            } else {
                const float m  = mask_val(masks, mfmt, (t + 1) * NBATCH + nIdx);
                const float hm = hnew * m;
                const size_t ho = (size_t)nxt * (NBATCH * HDIM) + (size_t)nIdx * HDIM + gj;
                hf[ho] = hm;
                const unsigned short hi = f2bf(hm);
                hhi[ho] = hi;
                hlo[ho] = f2bf(hm - bf2f(hi));
            }
        }

        if (t != TSTEPS - 1) {
            __syncthreads();
            if (tid == 0) {
                __threadfence();
                int a = __hip_atomic_fetch_add(bar_ctr, 1, __ATOMIC_ACQ_REL, SCOPE_AGENT);
                if (a == (int)gridDim.x - 1) {
                    __hip_atomic_store(bar_ctr, 0, __ATOMIC_RELAXED, SCOPE_AGENT);
                    __hip_atomic_store(bar_gen, t + 1, __ATOMIC_RELEASE, SCOPE_AGENT);
                } else {
                    while (__hip_atomic_load(bar_gen, __ATOMIC_ACQUIRE, SCOPE_AGENT) < t + 1) {
                        __builtin_amdgcn_s_sleep(16);
                    }
                }
            }
            __syncthreads();
        }
    }
}

extern "C" void kernel_launch(void* const* d_in, const int* in_sizes, int n_in,
                              void* d_out, int out_size, void* d_ws, size_t ws_size,
                              hipStream_t stream) {
    const float* x      = (const float*)d_in[0];
    const float* hidden = (const float*)d_in[1];
    const unsigned char* masks = (const unsigned char*)d_in[2];
    const float* wih    = (const float*)d_in[3];
    const float* whh    = (const float*)d_in[4];
    const float* bih    = (const float*)d_in[5];
    const float* bhh    = (const float*)d_in[6];
    float* out = (float*)d_out;
    char*  ws  = (char*)d_ws;

    hipMemsetAsync(ws, 0, 32768, stream);
    detect_mask<<<1, 256, 0, stream>>>(masks, (int*)(ws + MFLAG_OFF));
    conv_w<<<3072, 256, 0, stream>>>(wih, whh,
                                     (unsigned short*)(ws + WIH_OFF),
                                     (unsigned short*)(ws + WHH_OFF));
    init_h<<<128, 256, 0, stream>>>(hidden, masks, (const int*)(ws + MFLAG_OFF),
                                    (float*)(ws + HF_OFF),
                                    (unsigned short*)(ws + HHI_OFF),
                                    (unsigned short*)(ws + HLO_OFF),
                                    (unsigned*)(ws + HP_OFF));

    if (ws_size >= (size_t)WS_NEED) {
        gru_seq<<<256, 512, 0, stream>>>(x, masks,
                                         (const int*)(ws + MFLAG_OFF),
                                         bih, bhh,
                                         (const unsigned short*)(ws + WIH_OFF),
                                         (const unsigned short*)(ws + WHH_OFF),
                                         hidden, out,
                                         (unsigned*)(ws + HP_OFF),
                                         (unsigned*)(ws + FLAGS_OFF));
    } else {
        gru_main<<<64, 256, 0, stream>>>(x, masks, bih, bhh,
                                         (const unsigned short*)(ws + WIH_OFF),
                                         (const unsigned short*)(ws + WHH_OFF),
                                         out,
                                         (float*)(ws + HF_OFF),
                                         (unsigned short*)(ws + HHI_OFF),
                                         (unsigned short*)(ws + HLO_OFF),
                                         (int*)(ws + BAR_CTR_OFF), (int*)(ws + BAR_GEN_OFF),
                                         (const int*)(ws + MFLAG_OFF));
    }
}

// Round 11
// 3772.073 us; speedup vs baseline: 1.4425x; 1.0097x over previous
//
#include <hip/hip_runtime.h>

// Masked GRU (RNNStateEncoder), T=256, N=128, D=H=1024.
// Persistent step kernel: 256 WGs x 512 threads, WG = 32 rows x 16 h-cols.
// Round-11: round-9 base with the step body REORDERED so the pre-flag path
// holds only the true recurrence:
//   h-loads -> h-MFMAs -> gates -> h sc1 store -> vmcnt(0) (h only) -> flag
// and ALL slack work (xp GEMM for t+1 incl. x HBM loads, Pl reduce, mask
// prefetch, out store) moved after the flag, overlapping the barrier poll.
// h exchange: sc1 writes (L3), plain coalesced reads over a 128-buffer
// rotation (L2 self-evicts in ~8 steps << 128 -> never stale, no invalidates).
// Fallback (ws too small): round-2 monolithic persistent kernel.

#define TSTEPS 256
#define NBATCH 128
#define DDIM   1024
#define HDIM   1024
#define HPW    128          // rotation window (buffers)

typedef short  bf16x8 __attribute__((ext_vector_type(8)));
typedef float  f32x4  __attribute__((ext_vector_type(4)));
typedef unsigned long long ull;

// ---- ws layout (bytes) ----
#define BAR_CTR_OFF  0                          // fallback
#define BAR_GEN_OFF  4                          // fallback
#define MFLAG_OFF    2048
#define FLAGS_OFF    8192                       // 256 flags x 64B = 16KB
#define WIH_OFF      32768
#define WHH_OFF      (WIH_OFF + 6291456)        // 6324224
#define HF_OFF       12615680                   // fallback float h[2]
#define HHI_OFF      13664256                   // fallback
#define HLO_OFF      14188544                   // fallback
#define HP_OFF       14712832                   // u32 hp[128][128*1024]
#define HPBUF        131072ull                  // u32 elements per buffer
#define WS_NEED      (HP_OFF + (ull)HPW * 524288ull)   // ~82 MB

#define SCOPE_AGENT __HIP_MEMORY_SCOPE_AGENT

__device__ __forceinline__ unsigned short f2bf(float f) {
    union { float f; unsigned u; } v; v.f = f;
    unsigned r = v.u + 0x7FFFu + ((v.u >> 16) & 1u);   // RNE
    return (unsigned short)(r >> 16);
}
__device__ __forceinline__ float bf2f(unsigned short h) {
    union { unsigned u; float f; } v; v.u = ((unsigned)h) << 16;
    return v.f;
}

__device__ __forceinline__ float mask_val(const void* m, int fmt, int idx) {
    if (fmt == 0) return ((const unsigned char*)m)[idx] ? 1.f : 0.f;
    if (fmt == 1) return ((const int*)m)[idx] ? 1.f : 0.f;
    return (((const float*)m)[idx] != 0.f) ? 1.f : 0.f;
}

__device__ __forceinline__ void st_dev32(unsigned* p, unsigned v) {
    __hip_atomic_store(p, v, __ATOMIC_RELAXED, SCOPE_AGENT);   // sc1, bypass L2
}

// ---- detect mask dtype: 0 = bool bytes, 1 = int32, 2 = float32 ----
__global__ void detect_mask(const unsigned char* __restrict__ m8, int* __restrict__ flag) {
    __shared__ int s_ones, s_c01, s_cf;
    if (threadIdx.x == 0) { s_ones = 0; s_c01 = 0; s_cf = 0; }
    __syncthreads();
    int ones = 0;
    for (int i = threadIdx.x; i < 4096; i += 256) ones += (m8[i] == 1);
    int c01 = 0, cf = 0;
    const unsigned* m32 = (const unsigned*)m8;
    for (int i = threadIdx.x; i < 1024; i += 256) {
        unsigned v = m32[i];
        c01 += (v <= 1u);
        cf  += (v == 0u || v == 0x3F800000u);
    }
    atomicAdd(&s_ones, ones); atomicAdd(&s_c01, c01); atomicAdd(&s_cf, cf);
    __syncthreads();
    if (threadIdx.x == 0) *flag = (s_ones > 2048) ? 0 : ((s_c01 >= s_cf) ? 1 : 2);
}

// ---- convert both weight matrices to bf16 (row-major (3072,1024)) ----
__global__ void conv_w(const float* __restrict__ wih, const float* __restrict__ whh,
                       unsigned short* __restrict__ wih_b, unsigned short* __restrict__ whh_b) {
    size_t i = ((size_t)blockIdx.x * 256 + threadIdx.x) * 4;
    if (i >= (size_t)3145728) return;
    float4 a = *(const float4*)(wih + i);
    ushort4 ra; ra.x = f2bf(a.x); ra.y = f2bf(a.y); ra.z = f2bf(a.z); ra.w = f2bf(a.w);
    *(ushort4*)(wih_b + i) = ra;
    float4 b = *(const float4*)(whh + i);
    ushort4 rb; rb.x = f2bf(b.x); rb.y = f2bf(b.y); rb.z = f2bf(b.z); rb.w = f2bf(b.w);
    *(ushort4*)(whh_b + i) = rb;
}

// ---- init h0 (pre-masked with m[0]) ----
__global__ void init_h(const float* __restrict__ h0, const unsigned char* __restrict__ masks,
                       const int* __restrict__ flag,
                       float* __restrict__ hf, unsigned short* __restrict__ hhi,
                       unsigned short* __restrict__ hlo, unsigned* __restrict__ hp) {
    int i = (blockIdx.x * 256 + threadIdx.x) * 4;
    if (i >= NBATCH * HDIM) return;
    int fmt = *flag;
    int n = i >> 10;
    float m = mask_val(masks, fmt, n);
    float4 a = *(const float4*)(h0 + i);
    float v[4] = { a.x * m, a.y * m, a.z * m, a.w * m };
#pragma unroll
    for (int q = 0; q < 4; ++q) {
        hf[i + q] = v[q];
        unsigned short hi = f2bf(v[q]);
        unsigned short lo = f2bf(v[q] - bf2f(hi));
        hhi[i + q] = hi;
        hlo[i + q] = lo;
        hp[i + q] = ((unsigned)hi << 16) | (unsigned)lo;   // buffer 0
    }
}

// ============== main persistent GRU kernel: 256 WGs x 512 threads ==============
__launch_bounds__(512, 2)
__global__ void gru_seq(const float* __restrict__ x,
                        const unsigned char* __restrict__ masks,
                        const int* __restrict__ mflag,
                        const float* __restrict__ bih,
                        const float* __restrict__ bhh,
                        const unsigned short* __restrict__ wih,
                        const unsigned short* __restrict__ whh,
                        const float* __restrict__ h0,
                        float* __restrict__ out,
                        unsigned* __restrict__ hp,          // HPW rotating buffers
                        unsigned* __restrict__ flags) {
    const int bid  = blockIdx.x;
    // XCD mapping (dispatch round-robin bid%8): per XCD -> 16 cb x 2 rb.
    const int x7 = bid & 7;
    const int s5 = bid >> 3;                    // 0..31
    const int cb = ((x7 >> 1) << 4) | (s5 >> 1);   // 0..63 : 16 h-cols
    const int rb = ((x7 & 1) << 1) | (s5 & 1);     // 0..3  : 32 batch rows
    const int tid  = threadIdx.x;
    const int wave = tid >> 6;          // 0..7
    const int lane = tid & 63;
    const int l15  = lane & 15;
    const int l4   = lane >> 4;
    const int rt   = wave >> 2;         // row-tile 0..1
    const int kq   = wave & 3;          // K quarter 0..3
    const int mfmt = *mflag;
    const int an   = rb * 32 + rt * 16 + l15;    // A-fragment batch row

    __shared__ __align__(16) unsigned short Wl[49152];  // W_hh slice 48x1024, swizzled
    __shared__ __align__(16) f32x4 Pl[3][512];          // partials, XOR-swizzled

    // ---- stage W_hh slice into LDS ----
#pragma unroll
    for (int it = 0; it < 12; ++it) {
        const int ck = it * 512 + tid;          // 16B chunks
        const int sr = ck >> 7;                 // 0..47
        const int kc = ck & 127;
        const int grow = (sr >> 4) * 1024 + cb * 16 + (sr & 15);
        bf16x8 v = *(const bf16x8*)(whh + (size_t)grow * 1024 + kc * 8);
        const int byte = (sr * 2048 + kc * 16) ^ ((sr & 7) << 4);
        *(bf16x8*)((char*)Wl + byte) = v;
    }

    // ---- per-thread output mapping: 1 (row, col) each ----
    const int r = tid >> 4, c = tid & 15;
    const int n = rb * 32 + r;
    const int j = cb * 16 + c;
    const int rtp = r >> 4, ip = r & 3;
    const int lanep = ((r >> 2) & 3) * 16 + c;
    const float bir = bih[j], biz = bih[1024 + j], bin = bih[2048 + j];
    const float bhr = bhh[j], bhz = bhh[1024 + j], bhn = bhh[2048 + j];

    float hold = h0[(size_t)n * 1024 + j] * mask_val(masks, mfmt, n);
    float mn   = mask_val(masks, mfmt, NBATCH + n);     // mask[t=1]

    unsigned* myflag = flags + (rb * 64 + cb) * 16;     // 64B spacing
    unsigned* pollfl = flags + (rb * 64 + lane) * 16;   // wave0 lane -> one WG flag

    const f32x4 zz = {0.f, 0.f, 0.f, 0.f};
    const int widx  = wave * 64 + lane;
    const int wbyte = (widx * 16) ^ ((widx & 3) << 5);  // swizzled Pl write offset

    // xp GEMM for time tt (own slice, in registers; x/W_ih L2-cacheable)
    auto xp_compute = [&](int tt, f32x4* axx) {
        axx[0] = zz; axx[1] = zz; axx[2] = zz;
        const float* xrow = x + ((size_t)tt * NBATCH + an) * 1024 + kq * 256 + l4 * 8;
#pragma unroll
        for (int kt = 0; kt < 8; ++kt) {
            float4 u0 = *(const float4*)(xrow + kt * 32);
            float4 u1 = *(const float4*)(xrow + kt * 32 + 4);
            bf16x8 a;
            a[0] = (short)f2bf(u0.x); a[1] = (short)f2bf(u0.y);
            a[2] = (short)f2bf(u0.z); a[3] = (short)f2bf(u0.w);
            a[4] = (short)f2bf(u1.x); a[5] = (short)f2bf(u1.y);
            a[6] = (short)f2bf(u1.z); a[7] = (short)f2bf(u1.w);
#pragma unroll
            for (int ct = 0; ct < 3; ++ct) {
                const bf16x8 bw = *(const bf16x8*)(wih +
                    (size_t)(ct * 1024 + cb * 16 + l15) * 1024 + kq * 256 + kt * 32 + l4 * 8);
                axx[ct] = __builtin_amdgcn_mfma_f32_16x16x32_bf16(a, bw, axx[ct], 0, 0, 0);
            }
        }
    };
    // per-thread 4-way K reduction from swizzled Pl
    auto redx = [&](int ct) -> float {
        float s = 0.f;
#pragma unroll
        for (int q = 0; q < 4; ++q) {
            const int idx  = (rtp * 4 + q) * 64 + lanep;
            const int byte = ((idx * 16) ^ ((idx & 3) << 5)) + ip * 4;
            s += *(const float*)((const char*)Pl + ct * 8192 + byte);
        }
        return s;
    };

    // ---- prologue: xp[0] ----
    f32x4 axx[3];
    xp_compute(0, axx);
#pragma unroll
    for (int ct = 0; ct < 3; ++ct)
        *(f32x4*)((char*)Pl + ct * 8192 + wbyte) = axx[ct];
    __syncthreads();
    float xr  = redx(0) + bir;
    float xz  = redx(1) + biz;
    float xn_ = redx(2) + bin;
    __syncthreads();

    for (int t = 0; t < TSTEPS; ++t) {
        const unsigned* hp_c = hp + (size_t)(t & (HPW - 1)) * HPBUF;         // read h[t]
        unsigned*       hp_n = hp + (size_t)((t + 1) & (HPW - 1)) * HPBUF;   // write h[t+1]

        // 1. coalesced plain loads of h (L2-cached; rotation -> never stale)
        uint4 qa[8], qb[8];
        {
            const uint4* hq = (const uint4*)(hp_c + (size_t)an * 1024 + kq * 256 + l4 * 8);
#pragma unroll
            for (int kt = 0; kt < 8; ++kt) { qa[kt] = hq[kt * 8]; qb[kt] = hq[kt * 8 + 1]; }
        }

        // 2. h MFMAs immediately (no xp in between - x latency moved post-flag)
        f32x4 acch[3]; acch[0] = zz; acch[1] = zz; acch[2] = zz;
#pragma unroll
        for (int kt = 0; kt < 8; ++kt) {
            unsigned e[8];
            e[0] = qa[kt].x; e[1] = qa[kt].y; e[2] = qa[kt].z; e[3] = qa[kt].w;
            e[4] = qb[kt].x; e[5] = qb[kt].y; e[6] = qb[kt].z; e[7] = qb[kt].w;
            bf16x8 ah, al;
#pragma unroll
            for (int i = 0; i < 8; ++i) {
                ah[i] = (short)(e[i] >> 16);
                al[i] = (short)(e[i] & 0xFFFFu);
            }
            const int ktg = kq * 8 + kt;
#pragma unroll
            for (int ct = 0; ct < 3; ++ct) {
                const int sr = ct * 16 + l15;
                const int byte = (sr * 2048 + ktg * 64 + l4 * 16) ^ ((sr & 7) << 4);
                const bf16x8 bw = *(const bf16x8*)((char*)Wl + byte);
                acch[ct] = __builtin_amdgcn_mfma_f32_16x16x32_bf16(ah, bw, acch[ct], 0, 0, 0);
                acch[ct] = __builtin_amdgcn_mfma_f32_16x16x32_bf16(al, bw, acch[ct], 0, 0, 0);
            }
        }
#pragma unroll
        for (int ct = 0; ct < 3; ++ct)
            *(f32x4*)((char*)Pl + ct * 8192 + wbyte) = acch[ct];
        __syncthreads();                                        // #1: h partials ready

        // 3. gates
        const float hr = redx(0) + bhr;
        const float hz = redx(1) + bhz;
        const float hn = redx(2) + bhn;
        const float rg = 1.f / (1.f + __expf(-(xr + hr)));
        const float zg = 1.f / (1.f + __expf(-(xz + hz)));
        const float nc = tanhf(xn_ + rg * hn);
        const float hnew = (1.f - zg) * nc + zg * hold;

        if (t == TSTEPS - 1) {
            __builtin_nontemporal_store(hnew, &out[((size_t)t * NBATCH + n) * HDIM + j]);
            __builtin_nontemporal_store(hnew,
                &out[(size_t)TSTEPS * NBATCH * HDIM + (size_t)n * HDIM + j]);
        } else {
            // 4. recurrence store: the ONLY pre-flag VMEM
            const float hm = hnew * mn;
            hold = hm;
            const unsigned short hi = f2bf(hm);
            const unsigned short lo = f2bf(hm - bf2f(hi));
            st_dev32(&hp_n[(size_t)n * 1024 + j], ((unsigned)hi << 16) | (unsigned)lo);

            asm volatile("s_waitcnt vmcnt(0)" ::: "memory");    // h-store ack only
            __syncthreads();                                    // #2: all drained,
                                                                //     Pl reads done
            if (tid == 0)
                __hip_atomic_store(myflag, (unsigned)(t + 1), __ATOMIC_RELAXED, SCOPE_AGENT);

            // 5. slack work overlapping the barrier: xp[t+1] (x HBM latency
            //    hides under the poll), Pl reduce, mask prefetch, out store
            xp_compute(t + 1, axx);
#pragma unroll
            for (int ct = 0; ct < 3; ++ct)
                *(f32x4*)((char*)Pl + ct * 8192 + wbyte) = axx[ct];
            __syncthreads();                                    // #3: xp partials ready
            xr  = redx(0) + bir;
            xz  = redx(1) + biz;
            xn_ = redx(2) + bin;
            mn  = (t + 2 < TSTEPS) ? mask_val(masks, mfmt, (t + 2) * NBATCH + n) : 0.f;
            __builtin_nontemporal_store(hnew, &out[((size_t)t * NBATCH + n) * HDIM + j]);

            // 6. wave-parallel poll: lane L watches WG L of this rb-group
            if (wave == 0) {
                const unsigned tgt = (unsigned)(t + 1);
                while (true) {
                    unsigned v = __hip_atomic_load(pollfl, __ATOMIC_RELAXED, SCOPE_AGENT);
                    if (__all((int)(v >= tgt))) break;
                    __builtin_amdgcn_s_sleep(2);
                }
            }
            asm volatile("" ::: "memory");
            __syncthreads();                                    // #4: h[t+1] visible
        }
    }
}

// ============== Fallback: round-2 monolithic kernel (ws too small) ==============
__launch_bounds__(256)
__global__ void gru_main(const float* __restrict__ x,
                         const unsigned char* __restrict__ masks,
                         const float* __restrict__ bih, const float* __restrict__ bhh,
                         const unsigned short* __restrict__ wih,
                         const unsigned short* __restrict__ whh,
                         float* __restrict__ out,
                         float* __restrict__ hf,
                         unsigned short* __restrict__ hhi,
                         unsigned short* __restrict__ hlo,
                         int* __restrict__ bar_ctr, int* __restrict__ bar_gen,
                         const int* __restrict__ mflag) {
    const int bid  = blockIdx.x;
    const int xcd  = bid & 7;
    const int slot = bid >> 3;
    const int cb   = xcd * 2 + (slot >> 2);
    const int rb   = slot & 3;
    const int tid  = threadIdx.x;
    const int wid  = tid >> 6;
    const int lane = tid & 63;
    const int l15  = lane & 15;
    const int l4   = lane >> 4;
    const int mfmt = *mflag;

    __shared__ float xp_l[32][196];
    __shared__ float hp_l[32][196];

    int gbase[3];
#pragma unroll
    for (int c = 0; c < 3; ++c) {
        int ct = wid * 3 + c;
        gbase[c] = (ct >> 2) * 1024 + cb * 64 + (ct & 3) * 16;
    }

    for (int t = 0; t < TSTEPS; ++t) {
        const int cur = t & 1, nxt = cur ^ 1;
        f32x4 accx[2][3], acch[2][3];
        const f32x4 zz = {0.f, 0.f, 0.f, 0.f};
#pragma unroll
        for (int rt = 0; rt < 2; ++rt)
#pragma unroll
            for (int c = 0; c < 3; ++c) { accx[rt][c] = zz; acch[rt][c] = zz; }

        const unsigned short* hhi_c = hhi + (size_t)cur * (NBATCH * HDIM);
        const unsigned short* hlo_c = hlo + (size_t)cur * (NBATCH * HDIM);

        for (int kk = 0; kk < DDIM; kk += 32) {
            const int kb = kk + l4 * 8;
            bf16x8 axh[2], axl[2], ahh[2], ahl[2];
#pragma unroll
            for (int rt = 0; rt < 2; ++rt) {
                const int row = rb * 32 + rt * 16 + l15;
                const float* px = x + ((size_t)(t * NBATCH + row)) * DDIM + kb;
                float4 f0 = *(const float4*)px;
                float4 f1 = *(const float4*)(px + 4);
                float v[8] = { f0.x, f0.y, f0.z, f0.w, f1.x, f1.y, f1.z, f1.w };
#pragma unroll
                for (int qq = 0; qq < 8; ++qq) {
                    unsigned short hi = f2bf(v[qq]);
                    axh[rt][qq] = (short)hi;
                    axl[rt][qq] = (short)f2bf(v[qq] - bf2f(hi));
                }
                const size_t hoff = (size_t)row * HDIM + kb;
                ahh[rt] = *(const bf16x8*)(hhi_c + hoff);
                ahl[rt] = *(const bf16x8*)(hlo_c + hoff);
            }
#pragma unroll
            for (int c = 0; c < 3; ++c) {
                const size_t wrow = (size_t)(gbase[c] + l15) * 1024 + kb;
                const bf16x8 bx = *(const bf16x8*)(wih + wrow);
                const bf16x8 bh = *(const bf16x8*)(whh + wrow);
#pragma unroll
                for (int rt = 0; rt < 2; ++rt) {
                    accx[rt][c] = __builtin_amdgcn_mfma_f32_16x16x32_bf16(axh[rt], bx, accx[rt][c], 0, 0, 0);
                    accx[rt][c] = __builtin_amdgcn_mfma_f32_16x16x32_bf16(axl[rt], bx, accx[rt][c], 0, 0, 0);
                    acch[rt][c] = __builtin_amdgcn_mfma_f32_16x16x32_bf16(ahh[rt], bh, acch[rt][c], 0, 0, 0);
                    acch[rt][c] = __builtin_amdgcn_mfma_f32_16x16x32_bf16(ahl[rt], bh, acch[rt][c], 0, 0, 0);
                }
            }
        }

#pragma unroll
        for (int c = 0; c < 3; ++c) {
            const int ct = wid * 3 + c;
#pragma unroll
            for (int rt = 0; rt < 2; ++rt) {
#pragma unroll
                for (int i = 0; i < 4; ++i) {
                    const int row = rt * 16 + l4 * 4 + i;
                    const int col = ct * 16 + l15;
                    xp_l[row][col] = accx[rt][c][i];
                    hp_l[row][col] = acch[rt][c][i];
                }
            }
        }
        __syncthreads();

#pragma unroll
        for (int u = 0; u < 8; ++u) {
            const int o   = u * 256 + tid;
            const int row = o >> 6;
            const int jj  = o & 63;
            const int nIdx = rb * 32 + row;
            const int gj   = cb * 64 + jj;
            const float xr = xp_l[row][jj],       hr = hp_l[row][jj];
            const float xz = xp_l[row][64 + jj],  hz = hp_l[row][64 + jj];
            const float xn = xp_l[row][128 + jj], hn = hp_l[row][128 + jj];
            const float ar = xr + hr + bih[gj] + bhh[gj];
            const float az = xz + hz + bih[1024 + gj] + bhh[1024 + gj];
            const float rg = 1.f / (1.f + __expf(-ar));
            const float zg = 1.f / (1.f + __expf(-az));
            const float nc = tanhf(xn + bih[2048 + gj] + rg * (hn + bhh[2048 + gj]));
            const float hold = hf[(size_t)cur * (NBATCH * HDIM) + (size_t)nIdx * HDIM + gj];
            const float hnew = (1.f - zg) * nc + zg * hold;
            out[((size_t)t * NBATCH + nIdx) * HDIM + gj] = hnew;
            if (t == TSTEPS - 1) {
                out[(size_t)TSTEPS * NBATCH * HDIM + (size_t)nIdx * HDIM + gj] = hnew;
            } else {
                const float m  = mask_val(masks, mfmt, (t + 1) * NBATCH + nIdx);
                const float hm = hnew * m;
                const size_t ho = (size_t)nxt * (NBATCH * HDIM) + (size_t)nIdx * HDIM + gj;
                hf[ho] = hm;
                const unsigned short hi = f2bf(hm);
                hhi[ho] = hi;
                hlo[ho] = f2bf(hm - bf2f(hi));
            }
        }

        if (t != TSTEPS - 1) {
            __syncthreads();
            if (tid == 0) {
                __threadfence();
                int a = __hip_atomic_fetch_add(bar_ctr, 1, __ATOMIC_ACQ_REL, SCOPE_AGENT);
                if (a == (int)gridDim.x - 1) {
                    __hip_atomic_store(bar_ctr, 0, __ATOMIC_RELAXED, SCOPE_AGENT);
                    __hip_atomic_store(bar_gen, t + 1, __ATOMIC_RELEASE, SCOPE_AGENT);
                } else {
                    while (__hip_atomic_load(bar_gen, __ATOMIC_ACQUIRE, SCOPE_AGENT) < t + 1) {
                        __builtin_amdgcn_s_sleep(16);
                    }
                }
            }
            __syncthreads();
        }
    }
}

extern "C" void kernel_launch(void* const* d_in, const int* in_sizes, int n_in,
                              void* d_out, int out_size, void* d_ws, size_t ws_size,
                              hipStream_t stream) {
    const float* x      = (const float*)d_in[0];
    const float* hidden = (const float*)d_in[1];
    const unsigned char* masks = (const unsigned char*)d_in[2];
    const float* wih    = (const float*)d_in[3];
    const float* whh    = (const float*)d_in[4];
    const float* bih    = (const float*)d_in[5];
    const float* bhh    = (const float*)d_in[6];
    float* out = (float*)d_out;
    char*  ws  = (char*)d_ws;

    hipMemsetAsync(ws, 0, 32768, stream);
    detect_mask<<<1, 256, 0, stream>>>(masks, (int*)(ws + MFLAG_OFF));
    conv_w<<<3072, 256, 0, stream>>>(wih, whh,
                                     (unsigned short*)(ws + WIH_OFF),
                                     (unsigned short*)(ws + WHH_OFF));
    init_h<<<128, 256, 0, stream>>>(hidden, masks, (const int*)(ws + MFLAG_OFF),
                                    (float*)(ws + HF_OFF),
                                    (unsigned short*)(ws + HHI_OFF),
                                    (unsigned short*)(ws + HLO_OFF),
                                    (unsigned*)(ws + HP_OFF));

    if (ws_size >= (size_t)WS_NEED) {
        gru_seq<<<256, 512, 0, stream>>>(x, masks,
                                         (const int*)(ws + MFLAG_OFF),
                                         bih, bhh,
                                         (const unsigned short*)(ws + WIH_OFF),
                                         (const unsigned short*)(ws + WHH_OFF),
                                         hidden, out,
                                         (unsigned*)(ws + HP_OFF),
                                         (unsigned*)(ws + FLAGS_OFF));
    } else {
        gru_main<<<64, 256, 0, stream>>>(x, masks, bih, bhh,
                                         (const unsigned short*)(ws + WIH_OFF),
                                         (const unsigned short*)(ws + WHH_OFF),
                                         out,
                                         (float*)(ws + HF_OFF),
                                         (unsigned short*)(ws + HHI_OFF),
                                         (unsigned short*)(ws + HLO_OFF),
                                         (int*)(ws + BAR_CTR_OFF), (int*)(ws + BAR_GEN_OFF),
                                         (const int*)(ws + MFLAG_OFF));
    }
}

// Round 12
// 3711.139 us; speedup vs baseline: 1.4661x; 1.0164x over previous
//
#include <hip/hip_runtime.h>

// Masked GRU (RNNStateEncoder), T=256, N=128, D=H=1024.
// Persistent step kernel: 256 WGs x 512 threads, WG = 32 rows x 16 h-cols.
// Round-12: HIERARCHICAL barrier to kill sc1 poll-gather fabric contention.
//   Per rb-group (64 WGs): cb==0 WG's wave0 gathers the group's 64 flags and
//   publishes one gen[rb]; all other WGs poll gen[rb] with a SINGLE lane.
//   Poll traffic drops ~64x. Everything else = round-11 (passed, 3.93ms):
//   pre-flag path = recurrence only; xp GEMM/reduce/out-store overlap poll;
//   h sc1 writes + plain coalesced reads over 128-buffer rotation.
// Fallback (ws too small): round-2 monolithic persistent kernel.

#define TSTEPS 256
#define NBATCH 128
#define DDIM   1024
#define HDIM   1024
#define HPW    128          // rotation window (buffers)

typedef short  bf16x8 __attribute__((ext_vector_type(8)));
typedef float  f32x4  __attribute__((ext_vector_type(4)));
typedef unsigned long long ull;

// ---- ws layout (bytes) ----
#define BAR_CTR_OFF  0                          // fallback
#define BAR_GEN_OFF  4                          // fallback
#define MFLAG_OFF    2048
#define FLAGS_OFF    8192                       // 256 flags x 64B = 16KB
#define GEN_OFF      (FLAGS_OFF + 16384)        // 4 gen x 256B
#define WIH_OFF      32768
#define WHH_OFF      (WIH_OFF + 6291456)        // 6324224
#define HF_OFF       12615680                   // fallback float h[2]
#define HHI_OFF      13664256                   // fallback
#define HLO_OFF      14188544                   // fallback
#define HP_OFF       14712832                   // u32 hp[128][128*1024]
#define HPBUF        131072ull                  // u32 elements per buffer
#define WS_NEED      (HP_OFF + (ull)HPW * 524288ull)   // ~82 MB

#define SCOPE_AGENT __HIP_MEMORY_SCOPE_AGENT

__device__ __forceinline__ unsigned short f2bf(float f) {
    union { float f; unsigned u; } v; v.f = f;
    unsigned r = v.u + 0x7FFFu + ((v.u >> 16) & 1u);   // RNE
    return (unsigned short)(r >> 16);
}
__device__ __forceinline__ float bf2f(unsigned short h) {
    union { unsigned u; float f; } v; v.u = ((unsigned)h) << 16;
    return v.f;
}

__device__ __forceinline__ float mask_val(const void* m, int fmt, int idx) {
    if (fmt == 0) return ((const unsigned char*)m)[idx] ? 1.f : 0.f;
    if (fmt == 1) return ((const int*)m)[idx] ? 1.f : 0.f;
    return (((const float*)m)[idx] != 0.f) ? 1.f : 0.f;
}

__device__ __forceinline__ void st_dev32(unsigned* p, unsigned v) {
    __hip_atomic_store(p, v, __ATOMIC_RELAXED, SCOPE_AGENT);   // sc1, bypass L2
}

// ---- detect mask dtype: 0 = bool bytes, 1 = int32, 2 = float32 ----
__global__ void detect_mask(const unsigned char* __restrict__ m8, int* __restrict__ flag) {
    __shared__ int s_ones, s_c01, s_cf;
    if (threadIdx.x == 0) { s_ones = 0; s_c01 = 0; s_cf = 0; }
    __syncthreads();
    int ones = 0;
    for (int i = threadIdx.x; i < 4096; i += 256) ones += (m8[i] == 1);
    int c01 = 0, cf = 0;
    const unsigned* m32 = (const unsigned*)m8;
    for (int i = threadIdx.x; i < 1024; i += 256) {
        unsigned v = m32[i];
        c01 += (v <= 1u);
        cf  += (v == 0u || v == 0x3F800000u);
    }
    atomicAdd(&s_ones, ones); atomicAdd(&s_c01, c01); atomicAdd(&s_cf, cf);
    __syncthreads();
    if (threadIdx.x == 0) *flag = (s_ones > 2048) ? 0 : ((s_c01 >= s_cf) ? 1 : 2);
}

// ---- convert both weight matrices to bf16 (row-major (3072,1024)) ----
__global__ void conv_w(const float* __restrict__ wih, const float* __restrict__ whh,
                       unsigned short* __restrict__ wih_b, unsigned short* __restrict__ whh_b) {
    size_t i = ((size_t)blockIdx.x * 256 + threadIdx.x) * 4;
    if (i >= (size_t)3145728) return;
    float4 a = *(const float4*)(wih + i);
    ushort4 ra; ra.x = f2bf(a.x); ra.y = f2bf(a.y); ra.z = f2bf(a.z); ra.w = f2bf(a.w);
    *(ushort4*)(wih_b + i) = ra;
    float4 b = *(const float4*)(whh + i);
    ushort4 rb; rb.x = f2bf(b.x); rb.y = f2bf(b.y); rb.z = f2bf(b.z); rb.w = f2bf(b.w);
    *(ushort4*)(whh_b + i) = rb;
}

// ---- init h0 (pre-masked with m[0]) ----
__global__ void init_h(const float* __restrict__ h0, const unsigned char* __restrict__ masks,
                       const int* __restrict__ flag,
                       float* __restrict__ hf, unsigned short* __restrict__ hhi,
                       unsigned short* __restrict__ hlo, unsigned* __restrict__ hp) {
    int i = (blockIdx.x * 256 + threadIdx.x) * 4;
    if (i >= NBATCH * HDIM) return;
    int fmt = *flag;
    int n = i >> 10;
    float m = mask_val(masks, fmt, n);
    float4 a = *(const float4*)(h0 + i);
    float v[4] = { a.x * m, a.y * m, a.z * m, a.w * m };
#pragma unroll
    for (int q = 0; q < 4; ++q) {
        hf[i + q] = v[q];
        unsigned short hi = f2bf(v[q]);
        unsigned short lo = f2bf(v[q] - bf2f(hi));
        hhi[i + q] = hi;
        hlo[i + q] = lo;
        hp[i + q] = ((unsigned)hi << 16) | (unsigned)lo;   // buffer 0
    }
}

// ============== main persistent GRU kernel: 256 WGs x 512 threads ==============
__launch_bounds__(512, 2)
__global__ void gru_seq(const float* __restrict__ x,
                        const unsigned char* __restrict__ masks,
                        const int* __restrict__ mflag,
                        const float* __restrict__ bih,
                        const float* __restrict__ bhh,
                        const unsigned short* __restrict__ wih,
                        const unsigned short* __restrict__ whh,
                        const float* __restrict__ h0,
                        float* __restrict__ out,
                        unsigned* __restrict__ hp,          // HPW rotating buffers
                        unsigned* __restrict__ flags,
                        unsigned* __restrict__ gens) {
    const int bid  = blockIdx.x;
    // XCD mapping (dispatch round-robin bid%8): per XCD -> 16 cb x 2 rb.
    const int x7 = bid & 7;
    const int s5 = bid >> 3;                    // 0..31
    const int cb = ((x7 >> 1) << 4) | (s5 >> 1);   // 0..63 : 16 h-cols
    const int rb = ((x7 & 1) << 1) | (s5 & 1);     // 0..3  : 32 batch rows
    const int tid  = threadIdx.x;
    const int wave = tid >> 6;          // 0..7
    const int lane = tid & 63;
    const int l15  = lane & 15;
    const int l4   = lane >> 4;
    const int rt   = wave >> 2;         // row-tile 0..1
    const int kq   = wave & 3;          // K quarter 0..3
    const int mfmt = *mflag;
    const int an   = rb * 32 + rt * 16 + l15;    // A-fragment batch row
    const bool isAgg = (cb == 0);                 // aggregator WG of this rb-group

    __shared__ __align__(16) unsigned short Wl[49152];  // W_hh slice 48x1024, swizzled
    __shared__ __align__(16) f32x4 Pl[3][512];          // partials, XOR-swizzled

    // ---- stage W_hh slice into LDS ----
#pragma unroll
    for (int it = 0; it < 12; ++it) {
        const int ck = it * 512 + tid;          // 16B chunks
        const int sr = ck >> 7;                 // 0..47
        const int kc = ck & 127;
        const int grow = (sr >> 4) * 1024 + cb * 16 + (sr & 15);
        bf16x8 v = *(const bf16x8*)(whh + (size_t)grow * 1024 + kc * 8);
        const int byte = (sr * 2048 + kc * 16) ^ ((sr & 7) << 4);
        *(bf16x8*)((char*)Wl + byte) = v;
    }

    // ---- per-thread output mapping: 1 (row, col) each ----
    const int r = tid >> 4, c = tid & 15;
    const int n = rb * 32 + r;
    const int j = cb * 16 + c;
    const int rtp = r >> 4, ip = r & 3;
    const int lanep = ((r >> 2) & 3) * 16 + c;
    const float bir = bih[j], biz = bih[1024 + j], bin = bih[2048 + j];
    const float bhr = bhh[j], bhz = bhh[1024 + j], bhn = bhh[2048 + j];

    float hold = h0[(size_t)n * 1024 + j] * mask_val(masks, mfmt, n);
    float mn   = mask_val(masks, mfmt, NBATCH + n);     // mask[t=1]

    unsigned* myflag = flags + (rb * 64 + cb) * 16;     // 64B spacing
    unsigned* gatefl = flags + (rb * 64 + lane) * 16;   // aggregator lane -> WG flag
    unsigned* mygen  = gens + rb * 64;                  // 256B spacing

    const f32x4 zz = {0.f, 0.f, 0.f, 0.f};
    const int widx  = wave * 64 + lane;
    const int wbyte = (widx * 16) ^ ((widx & 3) << 5);  // swizzled Pl write offset

    // xp GEMM for time tt (own slice, in registers; x/W_ih L2-cacheable)
    auto xp_compute = [&](int tt, f32x4* axx) {
        axx[0] = zz; axx[1] = zz; axx[2] = zz;
        const float* xrow = x + ((size_t)tt * NBATCH + an) * 1024 + kq * 256 + l4 * 8;
#pragma unroll
        for (int kt = 0; kt < 8; ++kt) {
            float4 u0 = *(const float4*)(xrow + kt * 32);
            float4 u1 = *(const float4*)(xrow + kt * 32 + 4);
            bf16x8 a;
            a[0] = (short)f2bf(u0.x); a[1] = (short)f2bf(u0.y);
            a[2] = (short)f2bf(u0.z); a[3] = (short)f2bf(u0.w);
            a[4] = (short)f2bf(u1.x); a[5] = (short)f2bf(u1.y);
            a[6] = (short)f2bf(u1.z); a[7] = (short)f2bf(u1.w);
#pragma unroll
            for (int ct = 0; ct < 3; ++ct) {
                const bf16x8 bw = *(const bf16x8*)(wih +
                    (size_t)(ct * 1024 + cb * 16 + l15) * 1024 + kq * 256 + kt * 32 + l4 * 8);
                axx[ct] = __builtin_amdgcn_mfma_f32_16x16x32_bf16(a, bw, axx[ct], 0, 0, 0);
            }
        }
    };
    // per-thread 4-way K reduction from swizzled Pl
    auto redx = [&](int ct) -> float {
        float s = 0.f;
#pragma unroll
        for (int q = 0; q < 4; ++q) {
            const int idx  = (rtp * 4 + q) * 64 + lanep;
            const int byte = ((idx * 16) ^ ((idx & 3) << 5)) + ip * 4;
            s += *(const float*)((const char*)Pl + ct * 8192 + byte);
        }
        return s;
    };

    // ---- prologue: xp[0] ----
    f32x4 axx[3];
    xp_compute(0, axx);
#pragma unroll
    for (int ct = 0; ct < 3; ++ct)
        *(f32x4*)((char*)Pl + ct * 8192 + wbyte) = axx[ct];
    __syncthreads();
    float xr  = redx(0) + bir;
    float xz  = redx(1) + biz;
    float xn_ = redx(2) + bin;
    __syncthreads();

    for (int t = 0; t < TSTEPS; ++t) {
        const unsigned* hp_c = hp + (size_t)(t & (HPW - 1)) * HPBUF;         // read h[t]
        unsigned*       hp_n = hp + (size_t)((t + 1) & (HPW - 1)) * HPBUF;   // write h[t+1]

        // 1. coalesced plain loads of h (L2-cached; rotation -> never stale)
        uint4 qa[8], qb[8];
        {
            const uint4* hq = (const uint4*)(hp_c + (size_t)an * 1024 + kq * 256 + l4 * 8);
#pragma unroll
            for (int kt = 0; kt < 8; ++kt) { qa[kt] = hq[kt * 8]; qb[kt] = hq[kt * 8 + 1]; }
        }

        // 2. h MFMAs immediately
        f32x4 acch[3]; acch[0] = zz; acch[1] = zz; acch[2] = zz;
#pragma unroll
        for (int kt = 0; kt < 8; ++kt) {
            unsigned e[8];
            e[0] = qa[kt].x; e[1] = qa[kt].y; e[2] = qa[kt].z; e[3] = qa[kt].w;
            e[4] = qb[kt].x; e[5] = qb[kt].y; e[6] = qb[kt].z; e[7] = qb[kt].w;
            bf16x8 ah, al;
#pragma unroll
            for (int i = 0; i < 8; ++i) {
                ah[i] = (short)(e[i] >> 16);
                al[i] = (short)(e[i] & 0xFFFFu);
            }
            const int ktg = kq * 8 + kt;
#pragma unroll
            for (int ct = 0; ct < 3; ++ct) {
                const int sr = ct * 16 + l15;
                const int byte = (sr * 2048 + ktg * 64 + l4 * 16) ^ ((sr & 7) << 4);
                const bf16x8 bw = *(const bf16x8*)((char*)Wl + byte);
                acch[ct] = __builtin_amdgcn_mfma_f32_16x16x32_bf16(ah, bw, acch[ct], 0, 0, 0);
                acch[ct] = __builtin_amdgcn_mfma_f32_16x16x32_bf16(al, bw, acch[ct], 0, 0, 0);
            }
        }
#pragma unroll
        for (int ct = 0; ct < 3; ++ct)
            *(f32x4*)((char*)Pl + ct * 8192 + wbyte) = acch[ct];
        __syncthreads();                                        // #1: h partials ready

        // 3. gates
        const float hr = redx(0) + bhr;
        const float hz = redx(1) + bhz;
        const float hn = redx(2) + bhn;
        const float rg = 1.f / (1.f + __expf(-(xr + hr)));
        const float zg = 1.f / (1.f + __expf(-(xz + hz)));
        const float nc = tanhf(xn_ + rg * hn);
        const float hnew = (1.f - zg) * nc + zg * hold;

        if (t == TSTEPS - 1) {
            __builtin_nontemporal_store(hnew, &out[((size_t)t * NBATCH + n) * HDIM + j]);
            __builtin_nontemporal_store(hnew,
                &out[(size_t)TSTEPS * NBATCH * HDIM + (size_t)n * HDIM + j]);
        } else {
            // 4. recurrence store: the ONLY pre-flag VMEM
            const float hm = hnew * mn;
            hold = hm;
            const unsigned short hi = f2bf(hm);
            const unsigned short lo = f2bf(hm - bf2f(hi));
            st_dev32(&hp_n[(size_t)n * 1024 + j], ((unsigned)hi << 16) | (unsigned)lo);

            asm volatile("s_waitcnt vmcnt(0)" ::: "memory");    // h-store ack only
            __syncthreads();                                    // #2: all drained
            if (tid == 0)
                __hip_atomic_store(myflag, (unsigned)(t + 1), __ATOMIC_RELAXED, SCOPE_AGENT);

            // 5a. aggregator: wave0 gathers the group's 64 flags, publishes gen
            if (isAgg && wave == 0) {
                const unsigned tgt = (unsigned)(t + 1);
                while (true) {
                    unsigned v = __hip_atomic_load(gatefl, __ATOMIC_RELAXED, SCOPE_AGENT);
                    if (__all((int)(v >= tgt))) break;
                    __builtin_amdgcn_s_sleep(1);
                }
                if (lane == 0)
                    __hip_atomic_store(mygen, (unsigned)(t + 1), __ATOMIC_RELAXED, SCOPE_AGENT);
            }

            // 5b. slack work overlapping the barrier: xp[t+1], reduce, out store
            xp_compute(t + 1, axx);
#pragma unroll
            for (int ct = 0; ct < 3; ++ct)
                *(f32x4*)((char*)Pl + ct * 8192 + wbyte) = axx[ct];
            __syncthreads();                                    // #3: xp partials ready
            xr  = redx(0) + bir;
            xz  = redx(1) + biz;
            xn_ = redx(2) + bin;
            mn  = (t + 2 < TSTEPS) ? mask_val(masks, mfmt, (t + 2) * NBATCH + n) : 0.f;
            __builtin_nontemporal_store(hnew, &out[((size_t)t * NBATCH + n) * HDIM + j]);

            // 6. single-lane poll of the group's gen (1 address, 1 lane)
            if (tid == 0) {
                const unsigned tgt = (unsigned)(t + 1);
                while (__hip_atomic_load(mygen, __ATOMIC_RELAXED, SCOPE_AGENT) < tgt)
                    __builtin_amdgcn_s_sleep(1);
            }
            asm volatile("" ::: "memory");
            __syncthreads();                                    // #4: h[t+1] visible
        }
    }
}

// ============== Fallback: round-2 monolithic kernel (ws too small) ==============
__launch_bounds__(256)
__global__ void gru_main(const float* __restrict__ x,
                         const unsigned char* __restrict__ masks,
                         const float* __restrict__ bih, const float* __restrict__ bhh,
                         const unsigned short* __restrict__ wih,
                         const unsigned short* __restrict__ whh,
                         float* __restrict__ out,
                         float* __restrict__ hf,
                         unsigned short* __restrict__ hhi,
                         unsigned short* __restrict__ hlo,
                         int* __restrict__ bar_ctr, int* __restrict__ bar_gen,
                         const int* __restrict__ mflag) {
    const int bid  = blockIdx.x;
    const int xcd  = bid & 7;
    const int slot = bid >> 3;
    const int cb   = xcd * 2 + (slot >> 2);
    const int rb   = slot & 3;
    const int tid  = threadIdx.x;
    const int wid  = tid >> 6;
    const int lane = tid & 63;
    const int l15  = lane & 15;
    const int l4   = lane >> 4;
    const int mfmt = *mflag;

    __shared__ float xp_l[32][196];
    __shared__ float hp_l[32][196];

    int gbase[3];
#pragma unroll
    for (int c = 0; c < 3; ++c) {
        int ct = wid * 3 + c;
        gbase[c] = (ct >> 2) * 1024 + cb * 64 + (ct & 3) * 16;
    }

    for (int t = 0; t < TSTEPS; ++t) {
        const int cur = t & 1, nxt = cur ^ 1;
        f32x4 accx[2][3], acch[2][3];
        const f32x4 zz = {0.f, 0.f, 0.f, 0.f};
#pragma unroll
        for (int rt = 0; rt < 2; ++rt)
#pragma unroll
            for (int c = 0; c < 3; ++c) { accx[rt][c] = zz; acch[rt][c] = zz; }

        const unsigned short* hhi_c = hhi + (size_t)cur * (NBATCH * HDIM);
        const unsigned short* hlo_c = hlo + (size_t)cur * (NBATCH * HDIM);

        for (int kk = 0; kk < DDIM; kk += 32) {
            const int kb = kk + l4 * 8;
            bf16x8 axh[2], axl[2], ahh[2], ahl[2];
#pragma unroll
            for (int rt = 0; rt < 2; ++rt) {
                const int row = rb * 32 + rt * 16 + l15;
                const float* px = x + ((size_t)(t * NBATCH + row)) * DDIM + kb;
                float4 f0 = *(const float4*)px;
                float4 f1 = *(const float4*)(px + 4);
                float v[8] = { f0.x, f0.y, f0.z, f0.w, f1.x, f1.y, f1.z, f1.w };
#pragma unroll
                for (int qq = 0; qq < 8; ++qq) {
                    unsigned short hi = f2bf(v[qq]);
                    axh[rt][qq] = (short)hi;
                    axl[rt][qq] = (short)f2bf(v[qq] - bf2f(hi));
                }
                const size_t hoff = (size_t)row * HDIM + kb;
                ahh[rt] = *(const bf16x8*)(hhi_c + hoff);
                ahl[rt] = *(const bf16x8*)(hlo_c + hoff);
            }
#pragma unroll
            for (int c = 0; c < 3; ++c) {
                const size_t wrow = (size_t)(gbase[c] + l15) * 1024 + kb;
                const bf16x8 bx = *(const bf16x8*)(wih + wrow);
                const bf16x8 bh = *(const bf16x8*)(whh + wrow);
#pragma unroll
                for (int rt = 0; rt < 2; ++rt) {
                    accx[rt][c] = __builtin_amdgcn_mfma_f32_16x16x32_bf16(axh[rt], bx, accx[rt][c], 0, 0, 0);
                    accx[rt][c] = __builtin_amdgcn_mfma_f32_16x16x32_bf16(axl[rt], bx, accx[rt][c], 0, 0, 0);
                    acch[rt][c] = __builtin_amdgcn_mfma_f32_16x16x32_bf16(ahh[rt], bh, acch[rt][c], 0, 0, 0);
                    acch[rt][c] = __builtin_amdgcn_mfma_f32_16x16x32_bf16(ahl[rt], bh, acch[rt][c], 0, 0, 0);
                }
            }
        }

#pragma unroll
        for (int c = 0; c < 3; ++c) {
            const int ct = wid * 3 + c;
#pragma unroll
            for (int rt = 0; rt < 2; ++rt) {
#pragma unroll
                for (int i = 0; i < 4; ++i) {
                    const int row = rt * 16 + l4 * 4 + i;
                    const int col = ct * 16 + l15;
                    xp_l[row][col] = accx[rt][c][i];
                    hp_l[row][col] = acch[rt][c][i];
                }
            }
        }
        __syncthreads();

#pragma unroll
        for (int u = 0; u < 8; ++u) {
            const int o   = u * 256 + tid;
            const int row = o >> 6;
            const int jj  = o & 63;
            const int nIdx = rb * 32 + row;
            const int gj   = cb * 64 + jj;
            const float xr = xp_l[row][jj],       hr = hp_l[row][jj];
            const float xz = xp_l[row][64 + jj],  hz = hp_l[row][64 + jj];
            const float xn = xp_l[row][128 + jj], hn = hp_l[row][128 + jj];
            const float ar = xr + hr + bih[gj] + bhh[gj];
            const float az = xz + hz + bih[1024 + gj] + bhh[1024 + gj];
            const float rg = 1.f / (1.f + __expf(-ar));
            const float zg = 1.f / (1.f + __expf(-az));
            const float nc = tanhf(xn + bih[2048 + gj] + rg * (hn + bhh[2048 + gj]));
            const float hold = hf[(size_t)cur * (NBATCH * HDIM) + (size_t)nIdx * HDIM + gj];
            const float hnew = (1.f - zg) * nc + zg * hold;
            out[((size_t)t * NBATCH + nIdx) * HDIM + gj] = hnew;
            if (t == TSTEPS - 1) {
                out[(size_t)TSTEPS * NBATCH * HDIM + (size_t)nIdx * HDIM + gj] = hnew;
            } else {
                const float m  = mask_val(masks, mfmt, (t + 1) * NBATCH + nIdx);
                const float hm = hnew * m;
                const size_t ho = (size_t)nxt * (NBATCH * HDIM) + (size_t)nIdx * HDIM + gj;
                hf[ho] = hm;
                const unsigned short hi = f2bf(hm);
                hhi[ho] = hi;
                hlo[ho] = f2bf(hm - bf2f(hi));
            }
        }

        if (t != TSTEPS - 1) {
            __syncthreads();
            if (tid == 0) {
                __threadfence();
                int a = __hip_atomic_fetch_add(bar_ctr, 1, __ATOMIC_ACQ_REL, SCOPE_AGENT);
                if (a == (int)gridDim.x - 1) {
                    __hip_atomic_store(bar_ctr, 0, __ATOMIC_RELAXED, SCOPE_AGENT);
                    __hip_atomic_store(bar_gen, t + 1, __ATOMIC_RELEASE, SCOPE_AGENT);
                } else {
                    while (__hip_atomic_load(bar_gen, __ATOMIC_ACQUIRE, SCOPE_AGENT) < t + 1) {
                        __builtin_amdgcn_s_sleep(16);
                    }
                }
            }
            __syncthreads();
        }
    }
}

extern "C" void kernel_launch(void* const* d_in, const int* in_sizes, int n_in,
                              void* d_out, int out_size, void* d_ws, size_t ws_size,
                              hipStream_t stream) {
    const float* x      = (const float*)d_in[0];
    const float* hidden = (const float*)d_in[1];
    const unsigned char* masks = (const unsigned char*)d_in[2];
    const float* wih    = (const float*)d_in[3];
    const float* whh    = (const float*)d_in[4];
    const float* bih    = (const float*)d_in[5];
    const float* bhh    = (const float*)d_in[6];
    float* out = (float*)d_out;
    char*  ws  = (char*)d_ws;

    hipMemsetAsync(ws, 0, 32768, stream);
    detect_mask<<<1, 256, 0, stream>>>(masks, (int*)(ws + MFLAG_OFF));
    conv_w<<<3072, 256, 0, stream>>>(wih, whh,
                                     (unsigned short*)(ws + WIH_OFF),
                                     (unsigned short*)(ws + WHH_OFF));
    init_h<<<128, 256, 0, stream>>>(hidden, masks, (const int*)(ws + MFLAG_OFF),
                                    (float*)(ws + HF_OFF),
                                    (unsigned short*)(ws + HHI_OFF),
                                    (unsigned short*)(ws + HLO_OFF),
                                    (unsigned*)(ws + HP_OFF));

    if (ws_size >= (size_t)WS_NEED) {
        gru_seq<<<256, 512, 0, stream>>>(x, masks,
                                         (const int*)(ws + MFLAG_OFF),
                                         bih, bhh,
                                         (const unsigned short*)(ws + WIH_OFF),
                                         (const unsigned short*)(ws + WHH_OFF),
                                         hidden, out,
                                         (unsigned*)(ws + HP_OFF),
                                         (unsigned*)(ws + FLAGS_OFF),
                                         (unsigned*)(ws + GEN_OFF));
    } else {
        gru_main<<<64, 256, 0, stream>>>(x, masks, bih, bhh,
                                         (const unsigned short*)(ws + WIH_OFF),
                                         (const unsigned short*)(ws + WHH_OFF),
                                         out,
                                         (float*)(ws + HF_OFF),
                                         (unsigned short*)(ws + HHI_OFF),
                                         (unsigned short*)(ws + HLO_OFF),
                                         (int*)(ws + BAR_CTR_OFF), (int*)(ws + BAR_GEN_OFF),
                                         (const int*)(ws + MFLAG_OFF));
    }
}

// Round 13
// 3542.337 us; speedup vs baseline: 1.5360x; 1.0477x over previous
//
#include <hip/hip_runtime.h>

// Masked GRU (RNNStateEncoder), T=256, N=128, D=H=1024.
// Round-13: replace the persistent-kernel sc1 barrier spine with 256
// GRAPH-REPLAYED PER-STEP KERNELS. Cross-step ordering/coherence comes from
// same-stream kernel boundaries (CP-managed release/acquire) instead of
// hand-rolled sc1 flags+polls (rounds 3-12 all plateaued at ~15us/step).
//   Phase A: xproj_gemm (proven r4): xp = bf16(x)@W_ih^T + b_ih.
//   Phase B: 256x gru_step: 256 WGs x 512 thr, WG = 32 rows x 16 cols,
//     K quartered across waves, Pl LDS reduction (r12 math, proven),
//     W_hh fragments straight from L2 (no LDS staging), h ping-pong as
//     packed u32 (hi|lo bf16) double buffer, plain cached accesses only.
// Fallback (ws too small): round-2 monolithic persistent kernel.

#define TSTEPS 256
#define NBATCH 128
#define DDIM   1024
#define HDIM   1024

typedef short  bf16x8 __attribute__((ext_vector_type(8)));
typedef float  f32x4  __attribute__((ext_vector_type(4)));
typedef unsigned long long ull;

// ---- ws layout (bytes) ----
#define BAR_CTR_OFF  0                          // fallback
#define BAR_GEN_OFF  4                          // fallback
#define MFLAG_OFF    2048
#define WIH_OFF      32768
#define WHH_OFF      (WIH_OFF + 6291456)        // 6324224
#define HF_OFF       12615680                   // fallback float h[2]
#define HHI_OFF      13664256                   // fallback
#define HLO_OFF      14188544                   // fallback
#define HP2_OFF      14712832                   // u32 hp2[2][128*1024] = 1MB
#define XP_OFF       15761408                   // bf16 xp[32768*3072] = 201MB
#define WS_NEED      (XP_OFF + 201326592ull)    // 217088000 (~207MB; r10 proved available)

#define SCOPE_AGENT __HIP_MEMORY_SCOPE_AGENT

__device__ __forceinline__ unsigned short f2bf(float f) {
    union { float f; unsigned u; } v; v.f = f;
    unsigned r = v.u + 0x7FFFu + ((v.u >> 16) & 1u);   // RNE
    return (unsigned short)(r >> 16);
}
__device__ __forceinline__ float bf2f(unsigned short h) {
    union { unsigned u; float f; } v; v.u = ((unsigned)h) << 16;
    return v.f;
}

__device__ __forceinline__ float mask_val(const void* m, int fmt, int idx) {
    if (fmt == 0) return ((const unsigned char*)m)[idx] ? 1.f : 0.f;
    if (fmt == 1) return ((const int*)m)[idx] ? 1.f : 0.f;
    return (((const float*)m)[idx] != 0.f) ? 1.f : 0.f;
}

// ---- detect mask dtype: 0 = bool bytes, 1 = int32, 2 = float32 ----
__global__ void detect_mask(const unsigned char* __restrict__ m8, int* __restrict__ flag) {
    __shared__ int s_ones, s_c01, s_cf;
    if (threadIdx.x == 0) { s_ones = 0; s_c01 = 0; s_cf = 0; }
    __syncthreads();
    int ones = 0;
    for (int i = threadIdx.x; i < 4096; i += 256) ones += (m8[i] == 1);
    int c01 = 0, cf = 0;
    const unsigned* m32 = (const unsigned*)m8;
    for (int i = threadIdx.x; i < 1024; i += 256) {
        unsigned v = m32[i];
        c01 += (v <= 1u);
        cf  += (v == 0u || v == 0x3F800000u);
    }
    atomicAdd(&s_ones, ones); atomicAdd(&s_c01, c01); atomicAdd(&s_cf, cf);
    __syncthreads();
    if (threadIdx.x == 0) *flag = (s_ones > 2048) ? 0 : ((s_c01 >= s_cf) ? 1 : 2);
}

// ---- convert both weight matrices to bf16 (row-major (3072,1024)) ----
__global__ void conv_w(const float* __restrict__ wih, const float* __restrict__ whh,
                       unsigned short* __restrict__ wih_b, unsigned short* __restrict__ whh_b) {
    size_t i = ((size_t)blockIdx.x * 256 + threadIdx.x) * 4;
    if (i >= (size_t)3145728) return;
    float4 a = *(const float4*)(wih + i);
    ushort4 ra; ra.x = f2bf(a.x); ra.y = f2bf(a.y); ra.z = f2bf(a.z); ra.w = f2bf(a.w);
    *(ushort4*)(wih_b + i) = ra;
    float4 b = *(const float4*)(whh + i);
    ushort4 rb; rb.x = f2bf(b.x); rb.y = f2bf(b.y); rb.z = f2bf(b.z); rb.w = f2bf(b.w);
    *(ushort4*)(whh_b + i) = rb;
}

// ---- init h0 (pre-masked with m[0]) ----
__global__ void init_h(const float* __restrict__ h0, const unsigned char* __restrict__ masks,
                       const int* __restrict__ flag,
                       float* __restrict__ hf, unsigned short* __restrict__ hhi,
                       unsigned short* __restrict__ hlo, unsigned* __restrict__ hp) {
    int i = (blockIdx.x * 256 + threadIdx.x) * 4;
    if (i >= NBATCH * HDIM) return;
    int fmt = *flag;
    int n = i >> 10;
    float m = mask_val(masks, fmt, n);
    float4 a = *(const float4*)(h0 + i);
    float v[4] = { a.x * m, a.y * m, a.z * m, a.w * m };
#pragma unroll
    for (int q = 0; q < 4; ++q) {
        hf[i + q] = v[q];
        unsigned short hi = f2bf(v[q]);
        unsigned short lo = f2bf(v[q] - bf2f(hi));
        hhi[i + q] = hi;
        hlo[i + q] = lo;
        hp[i + q] = ((unsigned)hi << 16) | (unsigned)lo;   // ping-pong buffer 0
    }
}

// ============== Phase A: xp = bf16(x) @ W_ih^T + b_ih (bf16 out) ==============
// Field-proven (bench round 4): 128x128 tile, LDS dbuf, XOR swizzle.
__launch_bounds__(256)
__global__ void xproj_gemm(const float* __restrict__ x,
                           const unsigned short* __restrict__ wih_b,
                           const float* __restrict__ bih,
                           unsigned short* __restrict__ xp) {
    const int n0 = blockIdx.x * 128;
    const int m0 = blockIdx.y * 128;
    const int tid  = threadIdx.x;
    const int wave = tid >> 6;
    const int lane = tid & 63;
    const int l15  = lane & 15;
    const int l4   = lane >> 4;
    const int wr   = wave >> 1;
    const int wc   = wave & 1;

    __shared__ __align__(16) unsigned short Asm[2][4096];
    __shared__ __align__(16) unsigned short Bsm[2][4096];

    const int row0 = tid >> 2, kc0 = tid & 3;
    const int wb0 = ((row0 * 64 + kc0 * 16) ^ ((row0 & 7) << 4));
    const int wb1 = (((row0 + 64) * 64 + kc0 * 16) ^ (((row0 + 64) & 7) << 4));

    f32x4 acc[4][4];
    const f32x4 zz = {0.f, 0.f, 0.f, 0.f};
#pragma unroll
    for (int m = 0; m < 4; ++m)
#pragma unroll
        for (int n = 0; n < 4; ++n) acc[m][n] = zz;

    auto ldA = [&](int row, int kk) -> bf16x8 {
        const float* p = x + (size_t)(m0 + row) * 1024 + kk + kc0 * 8;
        float4 u0 = *(const float4*)p;
        float4 u1 = *(const float4*)(p + 4);
        bf16x8 r;
        r[0] = (short)f2bf(u0.x); r[1] = (short)f2bf(u0.y);
        r[2] = (short)f2bf(u0.z); r[3] = (short)f2bf(u0.w);
        r[4] = (short)f2bf(u1.x); r[5] = (short)f2bf(u1.y);
        r[6] = (short)f2bf(u1.z); r[7] = (short)f2bf(u1.w);
        return r;
    };

    {
        bf16x8 a0 = ldA(row0, 0);
        bf16x8 a1 = ldA(row0 + 64, 0);
        bf16x8 b0 = *(const bf16x8*)(wih_b + (size_t)(n0 + row0) * 1024 + kc0 * 8);
        bf16x8 b1 = *(const bf16x8*)(wih_b + (size_t)(n0 + row0 + 64) * 1024 + kc0 * 8);
        *(bf16x8*)((char*)Asm[0] + wb0) = a0;
        *(bf16x8*)((char*)Asm[0] + wb1) = a1;
        *(bf16x8*)((char*)Bsm[0] + wb0) = b0;
        *(bf16x8*)((char*)Bsm[0] + wb1) = b1;
    }
    __syncthreads();

    for (int kt = 0; kt < 32; ++kt) {
        const int cur = kt & 1;
        bf16x8 a0, a1, b0, b1;
        const bool pre = (kt < 31);
        if (pre) {
            const int kk = (kt + 1) * 32;
            a0 = ldA(row0, kk);
            a1 = ldA(row0 + 64, kk);
            b0 = *(const bf16x8*)(wih_b + (size_t)(n0 + row0) * 1024 + kk + kc0 * 8);
            b1 = *(const bf16x8*)(wih_b + (size_t)(n0 + row0 + 64) * 1024 + kk + kc0 * 8);
        }
        bf16x8 af[4], bfr[4];
#pragma unroll
        for (int m = 0; m < 4; ++m) {
            const int r = wr * 64 + m * 16 + l15;
            af[m] = *(const bf16x8*)((char*)Asm[cur] + ((r * 64 + l4 * 16) ^ ((r & 7) << 4)));
        }
#pragma unroll
        for (int n = 0; n < 4; ++n) {
            const int r = wc * 64 + n * 16 + l15;
            bfr[n] = *(const bf16x8*)((char*)Bsm[cur] + ((r * 64 + l4 * 16) ^ ((r & 7) << 4)));
        }
#pragma unroll
        for (int m = 0; m < 4; ++m)
#pragma unroll
            for (int n = 0; n < 4; ++n)
                acc[m][n] = __builtin_amdgcn_mfma_f32_16x16x32_bf16(af[m], bfr[n], acc[m][n], 0, 0, 0);
        if (pre) {
            const int nxt = cur ^ 1;
            *(bf16x8*)((char*)Asm[nxt] + wb0) = a0;
            *(bf16x8*)((char*)Asm[nxt] + wb1) = a1;
            *(bf16x8*)((char*)Bsm[nxt] + wb0) = b0;
            *(bf16x8*)((char*)Bsm[nxt] + wb1) = b1;
        }
        __syncthreads();
    }

#pragma unroll
    for (int n = 0; n < 4; ++n) {
        const int col = n0 + wc * 64 + n * 16 + l15;
        const float bv = bih[col];
#pragma unroll
        for (int m = 0; m < 4; ++m) {
#pragma unroll
            for (int i = 0; i < 4; ++i) {
                const int row = m0 + wr * 64 + m * 16 + l4 * 4 + i;
                xp[(size_t)row * 3072 + col] = f2bf(acc[m][n][i] + bv);
            }
        }
    }
}

// ============== Phase B: one GRU timestep per kernel launch ==============
// 256 WGs x 512 thr; WG (rb,cb) = 32 batch rows x 16 h-cols. No staging,
// no flags, no sc1 - plain cached loads/stores, cross-launch coherent.
__launch_bounds__(512)
__global__ void gru_step(const int t,
                         const unsigned short* __restrict__ xp,
                         const unsigned char* __restrict__ masks,
                         const int* __restrict__ mflag,
                         const float* __restrict__ bhh,
                         const unsigned short* __restrict__ whh,
                         float* __restrict__ out,
                         const unsigned* __restrict__ hcur,
                         unsigned* __restrict__ hnxt) {
    const int bid  = blockIdx.x;
    const int x7 = bid & 7;                        // XCD round-robin
    const int s5 = bid >> 3;
    const int cb = ((x7 >> 1) << 4) | (s5 >> 1);   // 0..63
    const int rb = ((x7 & 1) << 1) | (s5 & 1);     // 0..3
    const int tid  = threadIdx.x;
    const int wave = tid >> 6, lane = tid & 63;
    const int l15  = lane & 15, l4 = lane >> 4;
    const int rt   = wave >> 2;          // row-tile 0..1
    const int kq   = wave & 3;           // K quarter 0..3
    const int mfmt = *mflag;
    const int an   = rb * 32 + rt * 16 + l15;

    __shared__ __align__(16) f32x4 Pl[3][512];     // partials, XOR-swizzled

    // per-thread output mapping (r12 math, proven)
    const int r = tid >> 4, c = tid & 15;
    const int n = rb * 32 + r;
    const int j = cb * 16 + c;
    const int rtp = r >> 4, ip = r & 3;
    const int lanep = ((r >> 2) & 3) * 16 + c;

    const f32x4 zz = {0.f, 0.f, 0.f, 0.f};
    const int widx  = wave * 64 + lane;
    const int wbyte = (widx * 16) ^ ((widx & 3) << 5);

    // 1. h loads (plain; previous launch's writes are coherent)
    uint4 qa[8], qb[8];
    {
        const uint4* hq = (const uint4*)(hcur + (size_t)an * 1024 + kq * 256 + l4 * 8);
#pragma unroll
        for (int kt = 0; kt < 8; ++kt) { qa[kt] = hq[kt * 8]; qb[kt] = hq[kt * 8 + 1]; }
    }

    // 2. h MFMAs; W_hh fragments straight from global (L2-resident)
    size_t brow[3];
#pragma unroll
    for (int g = 0; g < 3; ++g)
        brow[g] = (size_t)(g * 1024 + cb * 16 + l15) * 1024 + kq * 256 + l4 * 8;

    f32x4 acc[3]; acc[0] = zz; acc[1] = zz; acc[2] = zz;
#pragma unroll
    for (int kt = 0; kt < 8; ++kt) {
        unsigned e[8];
        e[0] = qa[kt].x; e[1] = qa[kt].y; e[2] = qa[kt].z; e[3] = qa[kt].w;
        e[4] = qb[kt].x; e[5] = qb[kt].y; e[6] = qb[kt].z; e[7] = qb[kt].w;
        bf16x8 ah, al;
#pragma unroll
        for (int i = 0; i < 8; ++i) {
            ah[i] = (short)(e[i] >> 16);
            al[i] = (short)(e[i] & 0xFFFFu);
        }
#pragma unroll
        for (int g = 0; g < 3; ++g) {
            const bf16x8 bw = *(const bf16x8*)(whh + brow[g] + kt * 32);
            acc[g] = __builtin_amdgcn_mfma_f32_16x16x32_bf16(ah, bw, acc[g], 0, 0, 0);
            acc[g] = __builtin_amdgcn_mfma_f32_16x16x32_bf16(al, bw, acc[g], 0, 0, 0);
        }
    }
#pragma unroll
    for (int g = 0; g < 3; ++g)
        *(f32x4*)((char*)Pl + g * 8192 + wbyte) = acc[g];
    __syncthreads();

    // 3. K-reduce + gates (1 output/thread)
    float hsum[3];
#pragma unroll
    for (int g = 0; g < 3; ++g) {
        float s = 0.f;
#pragma unroll
        for (int q = 0; q < 4; ++q) {
            const int idx  = (rtp * 4 + q) * 64 + lanep;
            const int byte = ((idx * 16) ^ ((idx & 3) << 5)) + ip * 4;
            s += *(const float*)((const char*)Pl + g * 8192 + byte);
        }
        hsum[g] = s;
    }

    const size_t xpb = ((size_t)t * NBATCH + n) * 3072 + j;
    const float xr  = bf2f(xp[xpb]);
    const float xz  = bf2f(xp[xpb + 1024]);
    const float xn_ = bf2f(xp[xpb + 2048]);

    const unsigned hu = hcur[(size_t)n * 1024 + j];
    const float hold = bf2f((unsigned short)(hu >> 16)) + bf2f((unsigned short)(hu & 0xFFFFu));

    const float rg = 1.f / (1.f + __expf(-(xr + hsum[0] + bhh[j])));
    const float zg = 1.f / (1.f + __expf(-(xz + hsum[1] + bhh[1024 + j])));
    const float nc = tanhf(xn_ + rg * (hsum[2] + bhh[2048 + j]));
    const float hnew = (1.f - zg) * nc + zg * hold;

    out[((size_t)t * NBATCH + n) * HDIM + j] = hnew;
    if (t == TSTEPS - 1) {
        out[(size_t)TSTEPS * NBATCH * HDIM + (size_t)n * HDIM + j] = hnew;
    } else {
        const float hm = hnew * mask_val(masks, mfmt, (t + 1) * NBATCH + n);
        const unsigned short hi = f2bf(hm);
        const unsigned short lo = f2bf(hm - bf2f(hi));
        hnxt[(size_t)n * 1024 + j] = ((unsigned)hi << 16) | (unsigned)lo;
    }
}

// ============== Fallback: round-2 monolithic kernel (ws too small) ==============
__launch_bounds__(256)
__global__ void gru_main(const float* __restrict__ x,
                         const unsigned char* __restrict__ masks,
                         const float* __restrict__ bih, const float* __restrict__ bhh,
                         const unsigned short* __restrict__ wih,
                         const unsigned short* __restrict__ whh,
                         float* __restrict__ out,
                         float* __restrict__ hf,
                         unsigned short* __restrict__ hhi,
                         unsigned short* __restrict__ hlo,
                         int* __restrict__ bar_ctr, int* __restrict__ bar_gen,
                         const int* __restrict__ mflag) {
    const int bid  = blockIdx.x;
    const int xcd  = bid & 7;
    const int slot = bid >> 3;
    const int cb   = xcd * 2 + (slot >> 2);
    const int rb   = slot & 3;
    const int tid  = threadIdx.x;
    const int wid  = tid >> 6;
    const int lane = tid & 63;
    const int l15  = lane & 15;
    const int l4   = lane >> 4;
    const int mfmt = *mflag;

    __shared__ float xp_l[32][196];
    __shared__ float hp_l[32][196];

    int gbase[3];
#pragma unroll
    for (int c = 0; c < 3; ++c) {
        int ct = wid * 3 + c;
        gbase[c] = (ct >> 2) * 1024 + cb * 64 + (ct & 3) * 16;
    }

    for (int t = 0; t < TSTEPS; ++t) {
        const int cur = t & 1, nxt = cur ^ 1;
        f32x4 accx[2][3], acch[2][3];
        const f32x4 zz = {0.f, 0.f, 0.f, 0.f};
#pragma unroll
        for (int rt = 0; rt < 2; ++rt)
#pragma unroll
            for (int c = 0; c < 3; ++c) { accx[rt][c] = zz; acch[rt][c] = zz; }

        const unsigned short* hhi_c = hhi + (size_t)cur * (NBATCH * HDIM);
        const unsigned short* hlo_c = hlo + (size_t)cur * (NBATCH * HDIM);

        for (int kk = 0; kk < DDIM; kk += 32) {
            const int kb = kk + l4 * 8;
            bf16x8 axh[2], axl[2], ahh[2], ahl[2];
#pragma unroll
            for (int rt = 0; rt < 2; ++rt) {
                const int row = rb * 32 + rt * 16 + l15;
                const float* px = x + ((size_t)(t * NBATCH + row)) * DDIM + kb;
                float4 f0 = *(const float4*)px;
                float4 f1 = *(const float4*)(px + 4);
                float v[8] = { f0.x, f0.y, f0.z, f0.w, f1.x, f1.y, f1.z, f1.w };
#pragma unroll
                for (int qq = 0; qq < 8; ++qq) {
                    unsigned short hi = f2bf(v[qq]);
                    axh[rt][qq] = (short)hi;
                    axl[rt][qq] = (short)f2bf(v[qq] - bf2f(hi));
                }
                const size_t hoff = (size_t)row * HDIM + kb;
                ahh[rt] = *(const bf16x8*)(hhi_c + hoff);
                ahl[rt] = *(const bf16x8*)(hlo_c + hoff);
            }
#pragma unroll
            for (int c = 0; c < 3; ++c) {
                const size_t wrow = (size_t)(gbase[c] + l15) * 1024 + kb;
                const bf16x8 bx = *(const bf16x8*)(wih + wrow);
                const bf16x8 bh = *(const bf16x8*)(whh + wrow);
#pragma unroll
                for (int rt = 0; rt < 2; ++rt) {
                    accx[rt][c] = __builtin_amdgcn_mfma_f32_16x16x32_bf16(axh[rt], bx, accx[rt][c], 0, 0, 0);
                    accx[rt][c] = __builtin_amdgcn_mfma_f32_16x16x32_bf16(axl[rt], bx, accx[rt][c], 0, 0, 0);
                    acch[rt][c] = __builtin_amdgcn_mfma_f32_16x16x32_bf16(ahh[rt], bh, acch[rt][c], 0, 0, 0);
                    acch[rt][c] = __builtin_amdgcn_mfma_f32_16x16x32_bf16(ahl[rt], bh, acch[rt][c], 0, 0, 0);
                }
            }
        }

#pragma unroll
        for (int c = 0; c < 3; ++c) {
            const int ct = wid * 3 + c;
#pragma unroll
            for (int rt = 0; rt < 2; ++rt) {
#pragma unroll
                for (int i = 0; i < 4; ++i) {
                    const int row = rt * 16 + l4 * 4 + i;
                    const int col = ct * 16 + l15;
                    xp_l[row][col] = accx[rt][c][i];
                    hp_l[row][col] = acch[rt][c][i];
                }
            }
        }
        __syncthreads();

#pragma unroll
        for (int u = 0; u < 8; ++u) {
            const int o   = u * 256 + tid;
            const int row = o >> 6;
            const int jj  = o & 63;
            const int nIdx = rb * 32 + row;
            const int gj   = cb * 64 + jj;
            const float xr = xp_l[row][jj],       hr = hp_l[row][jj];
            const float xz = xp_l[row][64 + jj],  hz = hp_l[row][64 + jj];
            const float xn = xp_l[row][128 + jj], hn = hp_l[row][128 + jj];
            const float ar = xr + hr + bih[gj] + bhh[gj];
            const float az = xz + hz + bih[1024 + gj] + bhh[1024 + gj];
            const float rg = 1.f / (1.f + __expf(-ar));
            const float zg = 1.f / (1.f + __expf(-az));
            const float nc = tanhf(xn + bih[2048 + gj] + rg * (hn + bhh[2048 + gj]));
            const float hold = hf[(size_t)cur * (NBATCH * HDIM) + (size_t)nIdx * HDIM + gj];
            const float hnew = (1.f - zg) * nc + zg * hold;
            out[((size_t)t * NBATCH + nIdx) * HDIM + gj] = hnew;
            if (t == TSTEPS - 1) {
                out[(size_t)TSTEPS * NBATCH * HDIM + (size_t)nIdx * HDIM + gj] = hnew;
            } else {
                const float m  = mask_val(masks, mfmt, (t + 1) * NBATCH + nIdx);
                const float hm = hnew * m;
                const size_t ho = (size_t)nxt * (NBATCH * HDIM) + (size_t)nIdx * HDIM + gj;
                hf[ho] = hm;
                const unsigned short hi = f2bf(hm);
                hhi[ho] = hi;
                hlo[ho] = f2bf(hm - bf2f(hi));
            }
        }

        if (t != TSTEPS - 1) {
            __syncthreads();
            if (tid == 0) {
                __threadfence();
                int a = __hip_atomic_fetch_add(bar_ctr, 1, __ATOMIC_ACQ_REL, SCOPE_AGENT);
                if (a == (int)gridDim.x - 1) {
                    __hip_atomic_store(bar_ctr, 0, __ATOMIC_RELAXED, SCOPE_AGENT);
                    __hip_atomic_store(bar_gen, t + 1, __ATOMIC_RELEASE, SCOPE_AGENT);
                } else {
                    while (__hip_atomic_load(bar_gen, __ATOMIC_ACQUIRE, SCOPE_AGENT) < t + 1) {
                        __builtin_amdgcn_s_sleep(16);
                    }
                }
            }
            __syncthreads();
        }
    }
}

extern "C" void kernel_launch(void* const* d_in, const int* in_sizes, int n_in,
                              void* d_out, int out_size, void* d_ws, size_t ws_size,
                              hipStream_t stream) {
    const float* x      = (const float*)d_in[0];
    const float* hidden = (const float*)d_in[1];
    const unsigned char* masks = (const unsigned char*)d_in[2];
    const float* wih    = (const float*)d_in[3];
    const float* whh    = (const float*)d_in[4];
    const float* bih    = (const float*)d_in[5];
    const float* bhh    = (const float*)d_in[6];
    float* out = (float*)d_out;
    char*  ws  = (char*)d_ws;

    hipMemsetAsync(ws, 0, 32768, stream);
    detect_mask<<<1, 256, 0, stream>>>(masks, (int*)(ws + MFLAG_OFF));
    conv_w<<<3072, 256, 0, stream>>>(wih, whh,
                                     (unsigned short*)(ws + WIH_OFF),
                                     (unsigned short*)(ws + WHH_OFF));
    init_h<<<128, 256, 0, stream>>>(hidden, masks, (const int*)(ws + MFLAG_OFF),
                                    (float*)(ws + HF_OFF),
                                    (unsigned short*)(ws + HHI_OFF),
                                    (unsigned short*)(ws + HLO_OFF),
                                    (unsigned*)(ws + HP2_OFF));

    if (ws_size >= (size_t)WS_NEED) {
        xproj_gemm<<<dim3(24, 256), 256, 0, stream>>>(x,
                                                      (const unsigned short*)(ws + WIH_OFF),
                                                      bih,
                                                      (unsigned short*)(ws + XP_OFF));
        unsigned* hp2 = (unsigned*)(ws + HP2_OFF);
        for (int t = 0; t < TSTEPS; ++t) {
            const unsigned* hc = hp2 + (size_t)(t & 1) * 131072;
            unsigned*       hn = hp2 + (size_t)((t + 1) & 1) * 131072;
            gru_step<<<256, 512, 0, stream>>>(t,
                                              (const unsigned short*)(ws + XP_OFF),
                                              masks,
                                              (const int*)(ws + MFLAG_OFF),
                                              bhh,
                                              (const unsigned short*)(ws + WHH_OFF),
                                              out, hc, hn);
        }
    } else {
        gru_main<<<64, 256, 0, stream>>>(x, masks, bih, bhh,
                                         (const unsigned short*)(ws + WIH_OFF),
                                         (const unsigned short*)(ws + WHH_OFF),
                                         out,
                                         (float*)(ws + HF_OFF),
                                         (unsigned short*)(ws + HHI_OFF),
                                         (unsigned short*)(ws + HLO_OFF),
                                         (int*)(ws + BAR_CTR_OFF), (int*)(ws + BAR_GEN_OFF),
                                         (const int*)(ws + MFLAG_OFF));
    }
}